// Round 1
// baseline (961.104 us; speedup 1.0000x reference)
//
#include <hip/hip_runtime.h>
#include <hip/hip_bf16.h>

#define NN   200000
#define EE   3200000
#define FDIM 64
#define HDIM 256
#define DDIMC 768

// ---- workspace layout (word offsets, 4B words) ----
#define W_CNT   0          // 200000 i32  (zeroed)
#define W_C     200000     // 200000 f32
#define W_HIST  400000     // 65536 i32   (zeroed)
#define W_CANDN 465536     // 1 i32       (zeroed)
#define ZERO_WORDS 465537
#define W_FLAG  465544
#define W_THR   465552
#define W_DIS   465600     // 200000 f32
#define W_SCORE 665600     // 200000 f32
#define W_SBLK  865600     // 1024*64 f32
#define W_CKEY  931136     // 32768 u32
#define W_CIDX  963904     // 32768 i32
#define W_XT    996672     // 64*64 f32
#define W_WW    1000768    // 64*64 f32
#define W_S     1004864    // 64 f32
#define W_D     1004928    // 256 f32
#define W_LN    1005184    // 512 f32
#define W_H1    1005696    // 256 f32

#define CAPW 32768
#define CAPL 4096
#define XBLOCKS 1024
#define NDBLK 782   // ceil(200000/256)

// ---- helpers ----
__device__ __forceinline__ float ldf(const void* p, int i, int bf) {
  if (bf) return __bfloat162float(((const __hip_bfloat16*)p)[i]);
  return ((const float*)p)[i];
}
__device__ __forceinline__ void stf(void* p, int i, float v, int bf) {
  if (bf) ((__hip_bfloat16*)p)[i] = __float2bfloat16(v);
  else ((float*)p)[i] = v;
}
__device__ __forceinline__ float wsum(float v) {
#pragma unroll
  for (int m = 32; m >= 1; m >>= 1) v += __shfl_xor(v, m, 64);
  return v;
}
__device__ __forceinline__ unsigned sortkey(float f) {
  unsigned u = __float_as_uint(f);
  return (u & 0x80000000u) ? ~u : (u | 0x80000000u);
}

// ---- dtype detector: are float tensors stored as bf16? ----
__global__ void k_detect(const unsigned short* x16, int* flag) {
  __shared__ int cnt;
  if (threadIdx.x == 0) cnt = 0;
  __syncthreads();
  int ok = 0;
  for (int k = threadIdx.x; k < 512; k += 256) {
    unsigned short u = x16[2 * k];           // even u16: bf16 value, or f32 low-mantissa
    int e = (u >> 7) & 0xFF;
    if (u == 0 || (e >= 100 && e <= 150)) ok++;
  }
  atomicAdd(&cnt, ok);
  __syncthreads();
  if (threadIdx.x == 0) flag[0] = (cnt >= 400) ? 1 : 0;
}

// ---- in-degree counting over col ----
__global__ void k_deg(const int* __restrict__ col, int* __restrict__ cnt) {
  int i = blockIdx.x * blockDim.x + threadIdx.x;
  if (i < EE) atomicAdd(&cnt[col[i]], 1);
}

// ---- dis/c init over N, plus doc_fc matvec (independent work merged) ----
__global__ void k_dis_doc(const int* __restrict__ cnt, float* __restrict__ dis,
                          float* __restrict__ c, const void* docf, const void* dw,
                          const void* db, float* __restrict__ d, const int* flagp) {
  if (blockIdx.x < NDBLK) {
    int i = blockIdx.x * 256 + threadIdx.x;
    if (i < NN) {
      int deg = cnt[i] + 1;            // +1 self loop
      dis[i] = rsqrtf((float)deg);
      c[i] = 1.0f / (float)deg;        // dis^2 self-loop term
    }
  } else {
    int flag = flagp[0];
    int o = (blockIdx.x - NDBLK) * 4 + (threadIdx.x >> 6);  // 0..255
    int lane = threadIdx.x & 63;
    float acc = 0.f;
    for (int k = lane; k < DDIMC; k += 64) acc += ldf(docf, k, flag) * ldf(dw, o * DDIMC + k, flag);
    acc = wsum(acc);
    if (lane == 0) d[o] = fmaxf(acc + ldf(db, o, flag), 0.0f);
  }
}

// ---- c[row] += dis[row]*dis[col] over edges ----
__global__ void k_edge2(const int* __restrict__ row, const int* __restrict__ col,
                        const float* __restrict__ dis, float* __restrict__ c) {
  int i = blockIdx.x * blockDim.x + threadIdx.x;
  if (i < EE) {
    int r = row[i], cc = col[i];
    atomicAdd(&c[r], dis[r] * dis[cc]);
  }
}

// ---- fused x pass: score + histogram + s = sum c_i * x_i (per-block partials) ----
__global__ void k_x(const void* x, const void* pw, const float* __restrict__ c,
                    float* __restrict__ score, int* __restrict__ hist,
                    float* __restrict__ sblk, const int* flagp) {
  __shared__ float sred[4][64];
  int flag = flagp[0];
  int t = threadIdx.x;
  int lane = t & 63;
  int w = t >> 6;
  int wid = (blockIdx.x * 256 + t) >> 6;
  int nw = (gridDim.x * 256) >> 6;
  float pwl = ldf(pw, lane, flag);
  float inv = 1.0f / sqrtf(wsum(pwl * pwl));
  float sacc = 0.f;
  for (int r = wid; r < NN; r += nw) {
    float xv = ldf(x, r * 64 + lane, flag);
    float dot = wsum(xv * pwl);
    sacc += c[r] * xv;
    if (lane == 0) {
      float sc = dot * inv;
      score[r] = sc;
      atomicAdd(&hist[sortkey(sc) >> 16], 1);
    }
  }
  sred[w][lane] = sacc;
  __syncthreads();
  if (w == 0) sblk[blockIdx.x * 64 + lane] = sred[0][lane] + sred[1][lane] + sred[2][lane] + sred[3][lane];
}

// ---- threshold bin from histogram + finish s reduction ----
__global__ void k_thresh(const int* __restrict__ hist, int* __restrict__ thrB,
                         const float* __restrict__ sblk, float* __restrict__ svec) {
  __shared__ int part[256];
  __shared__ int segl[256];
  __shared__ int res2[2];
  __shared__ float sred[4][64];
  int t = threadIdx.x;
  {
    int f = t & 63, chunk = t >> 6;
    float acc = 0.f;
    for (int b = chunk; b < XBLOCKS; b += 4) acc += sblk[b * 64 + f];
    sred[chunk][f] = acc;
  }
  int ssum = 0;
  for (int j = 0; j < 256; j++) ssum += hist[t * 256 + j];
  part[t] = ssum;
  __syncthreads();
  if (t < 64) svec[t] = sred[0][t] + sred[1][t] + sred[2][t] + sred[3][t];
  if (t == 0) {
    int acc = 0, seg = 0, above = 0;
    for (int b = 255; b >= 0; b--) {
      if (acc + part[b] >= 64) { seg = b; above = acc; break; }
      acc += part[b];
    }
    res2[0] = seg; res2[1] = above;
  }
  __syncthreads();
  int seg = res2[0];
  segl[t] = hist[seg * 256 + t];
  __syncthreads();
  if (t == 0) {
    int acc = res2[1], B = seg * 256;
    for (int j = 255; j >= 0; j--) {
      acc += segl[j];
      if (acc >= 64) { B = seg * 256 + j; break; }
    }
    thrB[0] = B;
  }
}

// ---- collect candidates with bin >= threshold ----
__global__ void k_collect(const float* __restrict__ score, const int* __restrict__ thrB,
                          int* __restrict__ candn, unsigned* __restrict__ ckey,
                          int* __restrict__ cidx) {
  int i = blockIdx.x * blockDim.x + threadIdx.x;
  if (i >= NN) return;
  unsigned u = sortkey(score[i]);
  if ((int)(u >> 16) >= thrB[0]) {
    int p = atomicAdd(candn, 1);
    if (p < CAPW) { ckey[p] = u; cidx[p] = i; }
  }
}

// ---- exact top-64 selection + build x_tilde ----
__global__ void k_top(const int* __restrict__ candn, const unsigned* __restrict__ ckey,
                      const int* __restrict__ cidx, const void* x,
                      float* __restrict__ xt, const int* flagp) {
  __shared__ unsigned long long keys[CAPL];
  __shared__ unsigned long long red[256];
  __shared__ int perm[64];
  __shared__ float ts[64];
  int flag = flagp[0];
  int t = threadIdx.x;
  int M = candn[0];
  if (M > CAPL) M = CAPL;
  for (int j = t; j < CAPL; j += 256)
    keys[j] = (j < M) ? ((((unsigned long long)ckey[j]) << 32) |
                         (unsigned long long)(0xFFFFFFFFu - (unsigned)cidx[j]))
                      : 0ULL;
  __syncthreads();
  for (int r = 0; r < 64; r++) {
    unsigned long long best = 0ULL;
    for (int j = t; j < CAPL; j += 256) { unsigned long long k = keys[j]; if (k > best) best = k; }
    red[t] = best;
    __syncthreads();
    for (int s2 = 128; s2 > 0; s2 >>= 1) {
      if (t < s2) { if (red[t + s2] > red[t]) red[t] = red[t + s2]; }
      __syncthreads();
    }
    unsigned long long win = red[0];
    if (t == 0) {
      unsigned ku = (unsigned)(win >> 32);
      unsigned idx = 0xFFFFFFFFu - (unsigned)(win & 0xFFFFFFFFu);
      perm[r] = (int)idx;
      unsigned bits = (ku & 0x80000000u) ? (ku ^ 0x80000000u) : ~ku;
      ts[r] = tanhf(__uint_as_float(bits));
    }
    for (int j = t; j < CAPL; j += 256) if (keys[j] == win) keys[j] = 0ULL;
    __syncthreads();
  }
  for (int q = t; q < 4096; q += 256) {
    int j = q >> 6, f2 = q & 63;
    xt[q] = ldf(x, perm[j] * 64 + f2, flag) * ts[j];
  }
}

// ---- GRU cell -> evolved weight W [64,64] ----
__global__ void k_gru(const float* __restrict__ xt, const void* h0g, const void* wihg,
                      const void* whhg, const void* bihg, const void* bhhg,
                      float* __restrict__ Wout, const int* flagp) {
  __shared__ float wbuf[192 * 64];   // transposed: wbuf[f*192+o]
  __shared__ float xtr[4 * 64];
  __shared__ float h0r[4 * 64];
  int flag = flagp[0];
  int t = threadIdx.x;
  int j0 = blockIdx.x * 4;
  { int jj = t >> 6, f2 = t & 63;
    xtr[t] = xt[(j0 + jj) * 64 + f2];
    h0r[t] = ldf(h0g, (j0 + jj) * 64 + f2, flag); }
  for (int k = t; k < 12288; k += 256) { int f2 = k / 192, o = k % 192; wbuf[f2 * 192 + o] = ldf(wihg, o * 64 + f2, flag); }
  __syncthreads();
  int jl = t >> 6, c2 = t & 63;
  float xr = 0.f, xz = 0.f, xn = 0.f;
  for (int f2 = 0; f2 < 64; f2++) {
    float xv = xtr[jl * 64 + f2];
    const float* wr = &wbuf[f2 * 192];
    xr += xv * wr[c2]; xz += xv * wr[64 + c2]; xn += xv * wr[128 + c2];
  }
  __syncthreads();
  for (int k = t; k < 12288; k += 256) { int f2 = k / 192, o = k % 192; wbuf[f2 * 192 + o] = ldf(whhg, o * 64 + f2, flag); }
  __syncthreads();
  float hr = 0.f, hz = 0.f, hn = 0.f;
  for (int f2 = 0; f2 < 64; f2++) {
    float hv = h0r[jl * 64 + f2];
    const float* wr = &wbuf[f2 * 192];
    hr += hv * wr[c2]; hz += hv * wr[64 + c2]; hn += hv * wr[128 + c2];
  }
  xr += ldf(bihg, c2, flag); xz += ldf(bihg, 64 + c2, flag); xn += ldf(bihg, 128 + c2, flag);
  hr += ldf(bhhg, c2, flag); hz += ldf(bhhg, 64 + c2, flag); hn += ldf(bhhg, 128 + c2, flag);
  float rg = 1.f / (1.f + expf(-(xr + hr)));
  float zg = 1.f / (1.f + expf(-(xz + hz)));
  float nc = tanhf(xn + rg * hn);
  float h0v = h0r[jl * 64 + c2];
  Wout[(j0 + jl) * 64 + c2] = (1.f - zg) * nc + zg * h0v;
}

// ---- pooled -> g -> layernorm ----
__global__ void k_mid(const float* __restrict__ svec, const float* __restrict__ Wm,
                      const float* __restrict__ d, const void* gw, const void* gb,
                      const void* lng, const void* lnb, float* __restrict__ lnv,
                      const int* flagp) {
  __shared__ float pooled[64];
  __shared__ float fused[512];
  __shared__ float red[256];
  __shared__ float stats[2];
  int flag = flagp[0];
  int t = threadIdx.x;
  if (t < 64) {
    float a = 0.f;
    for (int f = 0; f < 64; f++) a += svec[f] * Wm[f * 64 + t];
    pooled[t] = a * (1.0f / (float)NN);
  }
  __syncthreads();
  { float a = 0.f;
    for (int c2 = 0; c2 < 64; c2++) a += pooled[c2] * ldf(gw, t * 64 + c2, flag);
    fused[t] = a + ldf(gb, t, flag); }
  fused[256 + t] = d[t];
  __syncthreads();
  float v0 = fused[t], v1 = fused[t + 256];
  red[t] = v0 + v1;
  __syncthreads();
  for (int s2 = 128; s2 > 0; s2 >>= 1) { if (t < s2) red[t] += red[t + s2]; __syncthreads(); }
  if (t == 0) stats[0] = red[0];
  __syncthreads();
  red[t] = v0 * v0 + v1 * v1;
  __syncthreads();
  for (int s2 = 128; s2 > 0; s2 >>= 1) { if (t < s2) red[t] += red[t + s2]; __syncthreads(); }
  if (t == 0) stats[1] = red[0];
  __syncthreads();
  float mu = stats[0] * (1.f / 512.f);
  float var = stats[1] * (1.f / 512.f) - mu * mu;
  float istd = rsqrtf(var + 1e-5f);
  lnv[t]       = (v0 - mu) * istd * ldf(lng, t, flag)       + ldf(lnb, t, flag);
  lnv[t + 256] = (v1 - mu) * istd * ldf(lng, t + 256, flag) + ldf(lnb, t + 256, flag);
}

// ---- fusion matvec: h1 = relu(ln @ fusion_w.T + b) ----
__global__ void k_fuse(const float* __restrict__ lnv, const void* fw, const void* fb,
                       float* __restrict__ h1, const int* flagp) {
  int flag = flagp[0];
  int o = (blockIdx.x * 256 + threadIdx.x) >> 6;   // 0..255
  int lane = threadIdx.x & 63;
  float acc = 0.f;
  for (int k = lane; k < 512; k += 64) acc += lnv[k] * ldf(fw, o * 512 + k, flag);
  acc = wsum(acc);
  if (lane == 0) h1[o] = fmaxf(acc + ldf(fb, o, flag), 0.0f);
}

// ---- task + time heads -> 17 outputs ----
__global__ void k_out(const float* __restrict__ h1g, const void* tw, const void* tb,
                      const void* tmw, const void* tmb, void* out, const int* flagp) {
  __shared__ float h1s[256];
  int flag = flagp[0];
  int t = threadIdx.x;
  h1s[t] = h1g[t];
  __syncthreads();
  int w = t >> 6, lane = t & 63;
  for (int o = w; o < 17; o += 4) {
    float acc = 0.f;
    if (o < 16) { for (int k = lane; k < 256; k += 64) acc += h1s[k] * ldf(tw, o * 256 + k, flag); }
    else        { for (int k = lane; k < 256; k += 64) acc += h1s[k] * ldf(tmw, k, flag); }
    acc = wsum(acc);
    if (lane == 0) {
      float bias = (o < 16) ? ldf(tb, o, flag) : ldf(tmb, 0, flag);
      stf(out, o, acc + bias, flag);
    }
  }
}

extern "C" void kernel_launch(void* const* d_in, const int* in_sizes, int n_in,
                              void* d_out, int out_size, void* d_ws, size_t ws_size,
                              hipStream_t stream) {
  const void* x    = d_in[0];
  const int*  ei   = (const int*)d_in[1];
  const void* docf = d_in[2];
  const void* pw   = d_in[3];
  const void* h0   = d_in[4];
  const void* wih  = d_in[5];
  const void* whh  = d_in[6];
  const void* bih  = d_in[7];
  const void* bhh  = d_in[8];
  const void* gw   = d_in[9];
  const void* gb   = d_in[10];
  const void* dw   = d_in[11];
  const void* db   = d_in[12];
  const void* lng  = d_in[13];
  const void* lnb  = d_in[14];
  const void* fw   = d_in[15];
  const void* fb   = d_in[16];
  const void* tw   = d_in[17];
  const void* tb   = d_in[18];
  const void* tmw  = d_in[19];
  const void* tmb  = d_in[20];

  float* wsf = (float*)d_ws;
  int*   wsi = (int*)d_ws;

  hipMemsetAsync(d_ws, 0, (size_t)ZERO_WORDS * 4, stream);
  k_detect<<<1, 256, 0, stream>>>((const unsigned short*)x, wsi + W_FLAG);
  k_deg<<<12500, 256, 0, stream>>>(ei + EE, wsi + W_CNT);
  k_dis_doc<<<NDBLK + 64, 256, 0, stream>>>(wsi + W_CNT, wsf + W_DIS, wsf + W_C,
                                            docf, dw, db, wsf + W_D, wsi + W_FLAG);
  k_edge2<<<12500, 256, 0, stream>>>(ei, ei + EE, wsf + W_DIS, wsf + W_C);
  k_x<<<XBLOCKS, 256, 0, stream>>>(x, pw, wsf + W_C, wsf + W_SCORE, wsi + W_HIST,
                                   wsf + W_SBLK, wsi + W_FLAG);
  k_thresh<<<1, 256, 0, stream>>>(wsi + W_HIST, wsi + W_THR, wsf + W_SBLK, wsf + W_S);
  k_collect<<<NDBLK, 256, 0, stream>>>(wsf + W_SCORE, wsi + W_THR, wsi + W_CANDN,
                                       (unsigned*)(wsi + W_CKEY), wsi + W_CIDX);
  k_top<<<1, 256, 0, stream>>>(wsi + W_CANDN, (const unsigned*)(wsi + W_CKEY),
                               wsi + W_CIDX, x, wsf + W_XT, wsi + W_FLAG);
  k_gru<<<16, 256, 0, stream>>>(wsf + W_XT, h0, wih, whh, bih, bhh, wsf + W_WW, wsi + W_FLAG);
  k_mid<<<1, 256, 0, stream>>>(wsf + W_S, wsf + W_WW, wsf + W_D, gw, gb, lng, lnb,
                               wsf + W_LN, wsi + W_FLAG);
  k_fuse<<<64, 256, 0, stream>>>(wsf + W_LN, fw, fb, wsf + W_H1, wsi + W_FLAG);
  k_out<<<1, 256, 0, stream>>>(wsf + W_H1, tw, tb, tmw, tmb, d_out, wsi + W_FLAG);
}

// Round 2
// 790.191 us; speedup vs baseline: 1.2163x; 1.2163x over previous
//
#include <hip/hip_runtime.h>
#include <hip/hip_bf16.h>

#define NN   200000
#define EE   3200000
#define DDIMC 768

// ---- workspace layout (word offsets) ----
#define W_CNT   0          // 200000 i32 (zeroed)
#define W_C     200000     // 200000 f32 (zeroed) -- tacc: sum dis_r*dis_c per row
#define W_HIST  400000     // 65536 i32 (zeroed)
#define W_CANDN 465536     // 1 i32 (zeroed)
#define W_S8    465544     // 8*64 f32 (zeroed) -- replicated svec accumulators
#define ZERO_WORDS 466056
#define W_FLAG  466056
#define W_THR   466057
#define W_S     466064     // 64 f32
#define W_SCORE 466200     // 200000 f32
#define W_CKEY  666200     // 4096 u32
#define W_CIDX  670296     // 4096 i32
#define W_XT    674392     // 64*64 f32
#define W_WW    678488     // 64*64 f32
#define W_D     682584     // 256 f32

#define CAPL 4096
#define XBLOCKS 1024
#define NDBLK 782
#define EBLK  12500

// ---- helpers ----
__device__ __forceinline__ float ldf(const void* p, int i, int bf) {
  if (bf) return __bfloat162float(((const __hip_bfloat16*)p)[i]);
  return ((const float*)p)[i];
}
__device__ __forceinline__ void stf(void* p, int i, float v, int bf) {
  if (bf) ((__hip_bfloat16*)p)[i] = __float2bfloat16(v);
  else ((float*)p)[i] = v;
}
__device__ __forceinline__ float wsum(float v) {
#pragma unroll
  for (int m = 32; m >= 1; m >>= 1) v += __shfl_xor(v, m, 64);
  return v;
}
__device__ __forceinline__ int wsumi(int v) {
#pragma unroll
  for (int m = 32; m >= 1; m >>= 1) v += __shfl_xor(v, m, 64);
  return v;
}
__device__ __forceinline__ unsigned sortkey(float f) {
  unsigned u = __float_as_uint(f);
  return (u & 0x80000000u) ? ~u : (u | 0x80000000u);
}

// ---- dtype detector: are float tensors stored as bf16? ----
__global__ void k_detect(const unsigned short* x16, int* flag) {
  __shared__ int cnt;
  if (threadIdx.x == 0) cnt = 0;
  __syncthreads();
  int ok = 0;
  for (int k = threadIdx.x; k < 512; k += 256) {
    unsigned short u = x16[2 * k];
    int e = (u >> 7) & 0xFF;
    if (u == 0 || (e >= 100 && e <= 150)) ok++;
  }
  atomicAdd(&cnt, ok);
  __syncthreads();
  if (threadIdx.x == 0) flag[0] = (cnt >= 400) ? 1 : 0;
}

// ---- in-degree counting over col + doc_fc matvec (independent, merged) ----
__global__ void k_deg_doc(const int* __restrict__ col, int* __restrict__ cnt,
                          const void* docf, const void* dw, const void* db,
                          float* __restrict__ d, const int* flagp) {
  if (blockIdx.x < EBLK) {
    int i = blockIdx.x * 256 + threadIdx.x;
    if (i < EE) atomicAdd(&cnt[col[i]], 1);
  } else {
    int flag = flagp[0];
    int o = (blockIdx.x - EBLK) * 4 + (threadIdx.x >> 6);  // 0..255
    int lane = threadIdx.x & 63;
    float acc = 0.f;
    for (int k = lane; k < DDIMC; k += 64) acc += ldf(docf, k, flag) * ldf(dw, o * DDIMC + k, flag);
    acc = wsum(acc);
    if (lane == 0) d[o] = fmaxf(acc + ldf(db, o, flag), 0.0f);
  }
}

// ---- tacc[row] += dis[row]*dis[col], dis computed on the fly ----
__global__ void k_edge2(const int* __restrict__ row, const int* __restrict__ col,
                        const int* __restrict__ cnt, float* __restrict__ tacc) {
  int i = blockIdx.x * blockDim.x + threadIdx.x;
  if (i < EE) {
    int r = row[i], cc = col[i];
    float dr = rsqrtf((float)(cnt[r] + 1));
    float dc = rsqrtf((float)(cnt[cc] + 1));
    atomicAdd(&tacc[r], dr * dc);
  }
}

// ---- fused x pass: score + histogram + s = sum c_i * x_i ----
__global__ void k_x(const void* x, const void* pw, const float* __restrict__ tacc,
                    const int* __restrict__ cnt, float* __restrict__ score,
                    int* __restrict__ hist, float* __restrict__ s8, const int* flagp) {
  __shared__ float sred[4][64];
  int flag = flagp[0];
  int t = threadIdx.x;
  int lane = t & 63;
  int w = t >> 6;
  int wid = (blockIdx.x * 256 + t) >> 6;
  int nw = (gridDim.x * 256) >> 6;
  float pwl = ldf(pw, lane, flag);
  float inv = 1.0f / sqrtf(wsum(pwl * pwl));
  float sacc = 0.f;
  for (int r = wid; r < NN; r += nw) {
    float xv = ldf(x, r * 64 + lane, flag);
    float dot = wsum(xv * pwl);
    float cr = tacc[r] + 1.0f / (float)(cnt[r] + 1);
    sacc += cr * xv;
    if (lane == 0) {
      float sc = dot * inv;
      score[r] = sc;
      atomicAdd(&hist[sortkey(sc) >> 16], 1);
    }
  }
  sred[w][lane] = sacc;
  __syncthreads();
  if (w == 0)
    atomicAdd(&s8[(blockIdx.x & 7) * 64 + lane],
              sred[0][lane] + sred[1][lane] + sred[2][lane] + sred[3][lane]);
}

// ---- threshold bin from histogram + fold svec replicas ----
__global__ void k_thresh(const int* __restrict__ hist, int* __restrict__ thrB,
                         const float* __restrict__ s8, float* __restrict__ svec) {
  __shared__ int part[256];
  __shared__ int segl[256];
  __shared__ int res2[2];
  int t = threadIdx.x, w = t >> 6, lane = t & 63;
  if (t < 64) {
    float a = 0.f;
    for (int r = 0; r < 8; r++) a += s8[r * 64 + t];
    svec[t] = a;
  }
  for (int m = w; m < 256; m += 4) {
    const int* hb = &hist[m * 256];
    int a = hb[lane] + hb[lane + 64] + hb[lane + 128] + hb[lane + 192];
    a = wsumi(a);
    if (lane == 0) part[m] = a;
  }
  __syncthreads();
  if (t == 0) {
    int acc = 0, seg = 0, above = 0;
    for (int b = 255; b >= 0; b--) {
      if (acc + part[b] >= 64) { seg = b; above = acc; break; }
      acc += part[b];
    }
    res2[0] = seg; res2[1] = above;
  }
  __syncthreads();
  segl[t] = hist[res2[0] * 256 + t];
  __syncthreads();
  if (t == 0) {
    int acc = res2[1], B = res2[0] * 256;
    for (int j = 255; j >= 0; j--) {
      acc += segl[j];
      if (acc >= 64) { B = res2[0] * 256 + j; break; }
    }
    thrB[0] = B;
  }
}

// ---- collect candidates with bin >= threshold ----
__global__ void k_collect(const float* __restrict__ score, const int* __restrict__ thrB,
                          int* __restrict__ candn, unsigned* __restrict__ ckey,
                          int* __restrict__ cidx) {
  int i = blockIdx.x * blockDim.x + threadIdx.x;
  if (i >= NN) return;
  unsigned u = sortkey(score[i]);
  if ((int)(u >> 16) >= thrB[0]) {
    int p = atomicAdd(candn, 1);
    if (p < CAPL) { ckey[p] = u; cidx[p] = i; }
  }
}

// ---- exact top-64 via rank (O(M^2), M ~ 100) + build x_tilde ----
__global__ void k_top(const int* __restrict__ candn, const unsigned* __restrict__ ckey,
                      const int* __restrict__ cidx, const void* x,
                      float* __restrict__ xt, const int* flagp) {
  __shared__ unsigned long long keys[CAPL];
  __shared__ int perm[64];
  __shared__ float ts[64];
  int flag = flagp[0];
  int t = threadIdx.x;
  int M = candn[0];
  if (M > CAPL) M = CAPL;
  for (int j = t; j < M; j += 256)
    keys[j] = (((unsigned long long)ckey[j]) << 32) |
              (unsigned long long)(0xFFFFFFFFu - (unsigned)cidx[j]);
  __syncthreads();
  for (int j = t; j < M; j += 256) {
    unsigned long long k = keys[j];
    int rank = 0;
    for (int i = 0; i < M; i++) rank += (keys[i] > k) ? 1 : 0;
    if (rank < 64) {
      unsigned ku = (unsigned)(k >> 32);
      unsigned idx = 0xFFFFFFFFu - (unsigned)(k & 0xFFFFFFFFu);
      perm[rank] = (int)idx;
      unsigned bits = (ku & 0x80000000u) ? (ku ^ 0x80000000u) : ~ku;
      ts[rank] = tanhf(__uint_as_float(bits));
    }
  }
  __syncthreads();
  for (int q = t; q < 4096; q += 256) {
    int j = q >> 6, f2 = q & 63;
    xt[q] = ldf(x, perm[j] * 64 + f2, flag) * ts[j];
  }
}

// ---- GRU cell -> evolved weight W [64,64] ----
__global__ void k_gru(const float* __restrict__ xt, const void* h0g, const void* wihg,
                      const void* whhg, const void* bihg, const void* bhhg,
                      float* __restrict__ Wout, const int* flagp) {
  __shared__ float wbuf[192 * 64];   // transposed: wbuf[f*192+o]
  __shared__ float xtr[4 * 64];
  __shared__ float h0r[4 * 64];
  int flag = flagp[0];
  int t = threadIdx.x;
  int j0 = blockIdx.x * 4;
  { int jj = t >> 6, f2 = t & 63;
    xtr[t] = xt[(j0 + jj) * 64 + f2];
    h0r[t] = ldf(h0g, (j0 + jj) * 64 + f2, flag); }
  for (int k = t; k < 12288; k += 256) { int f2 = k / 192, o = k % 192; wbuf[f2 * 192 + o] = ldf(wihg, o * 64 + f2, flag); }
  __syncthreads();
  int jl = t >> 6, c2 = t & 63;
  float xr = 0.f, xz = 0.f, xn = 0.f;
  for (int f2 = 0; f2 < 64; f2++) {
    float xv = xtr[jl * 64 + f2];
    const float* wr = &wbuf[f2 * 192];
    xr += xv * wr[c2]; xz += xv * wr[64 + c2]; xn += xv * wr[128 + c2];
  }
  __syncthreads();
  for (int k = t; k < 12288; k += 256) { int f2 = k / 192, o = k % 192; wbuf[f2 * 192 + o] = ldf(whhg, o * 64 + f2, flag); }
  __syncthreads();
  float hr = 0.f, hz = 0.f, hn = 0.f;
  for (int f2 = 0; f2 < 64; f2++) {
    float hv = h0r[jl * 64 + f2];
    const float* wr = &wbuf[f2 * 192];
    hr += hv * wr[c2]; hz += hv * wr[64 + c2]; hn += hv * wr[128 + c2];
  }
  xr += ldf(bihg, c2, flag); xz += ldf(bihg, 64 + c2, flag); xn += ldf(bihg, 128 + c2, flag);
  hr += ldf(bhhg, c2, flag); hz += ldf(bhhg, 64 + c2, flag); hn += ldf(bhhg, 128 + c2, flag);
  float rg = 1.f / (1.f + expf(-(xr + hr)));
  float zg = 1.f / (1.f + expf(-(xz + hz)));
  float nc = tanhf(xn + rg * hn);
  float h0v = h0r[jl * 64 + c2];
  Wout[(j0 + jl) * 64 + c2] = (1.f - zg) * nc + zg * h0v;
}

// ---- tail: pooled -> g -> LN -> fusion -> heads (1 block) ----
__global__ void k_tail(const float* __restrict__ svec, const float* __restrict__ Wm,
                       const float* __restrict__ d, const void* gw, const void* gb,
                       const void* lng, const void* lnb, const void* fw, const void* fb,
                       const void* tw, const void* tb, const void* tmw, const void* tmb,
                       void* out, const int* flagp) {
  __shared__ float pooled[64];
  __shared__ float lnv[512];
  __shared__ float red[256];
  __shared__ float stats[2];
  __shared__ float h1s[256];
  int flag = flagp[0];
  int t = threadIdx.x;
  if (t < 64) {
    float a = 0.f;
    for (int f = 0; f < 64; f++) a += svec[f] * Wm[f * 64 + t];
    pooled[t] = a * (1.0f / (float)NN);
  }
  __syncthreads();
  float v0;
  { float a = 0.f;
    for (int c2 = 0; c2 < 64; c2++) a += pooled[c2] * ldf(gw, t * 64 + c2, flag);
    v0 = a + ldf(gb, t, flag); }
  float v1 = d[t];
  red[t] = v0 + v1;
  __syncthreads();
  for (int s2 = 128; s2 > 0; s2 >>= 1) { if (t < s2) red[t] += red[t + s2]; __syncthreads(); }
  if (t == 0) stats[0] = red[0];
  __syncthreads();
  red[t] = v0 * v0 + v1 * v1;
  __syncthreads();
  for (int s2 = 128; s2 > 0; s2 >>= 1) { if (t < s2) red[t] += red[t + s2]; __syncthreads(); }
  if (t == 0) stats[1] = red[0];
  __syncthreads();
  float mu = stats[0] * (1.f / 512.f);
  float var = stats[1] * (1.f / 512.f) - mu * mu;
  float istd = rsqrtf(var + 1e-5f);
  lnv[t]       = (v0 - mu) * istd * ldf(lng, t, flag)       + ldf(lnb, t, flag);
  lnv[t + 256] = (v1 - mu) * istd * ldf(lng, t + 256, flag) + ldf(lnb, t + 256, flag);
  __syncthreads();
  int w = t >> 6, lane = t & 63;
  for (int o = w; o < 256; o += 4) {
    float acc = 0.f;
    for (int k = lane; k < 512; k += 64) acc += lnv[k] * ldf(fw, o * 512 + k, flag);
    acc = wsum(acc);
    if (lane == 0) h1s[o] = fmaxf(acc + ldf(fb, o, flag), 0.0f);
  }
  __syncthreads();
  for (int o = w; o < 17; o += 4) {
    float acc = 0.f;
    if (o < 16) { for (int k = lane; k < 256; k += 64) acc += h1s[k] * ldf(tw, o * 256 + k, flag); }
    else        { for (int k = lane; k < 256; k += 64) acc += h1s[k] * ldf(tmw, k, flag); }
    acc = wsum(acc);
    if (lane == 0) {
      float bias = (o < 16) ? ldf(tb, o, flag) : ldf(tmb, 0, flag);
      stf(out, o, acc + bias, flag);
    }
  }
}

extern "C" void kernel_launch(void* const* d_in, const int* in_sizes, int n_in,
                              void* d_out, int out_size, void* d_ws, size_t ws_size,
                              hipStream_t stream) {
  const void* x    = d_in[0];
  const int*  ei   = (const int*)d_in[1];
  const void* docf = d_in[2];
  const void* pw   = d_in[3];
  const void* h0   = d_in[4];
  const void* wih  = d_in[5];
  const void* whh  = d_in[6];
  const void* bih  = d_in[7];
  const void* bhh  = d_in[8];
  const void* gw   = d_in[9];
  const void* gb   = d_in[10];
  const void* dw   = d_in[11];
  const void* db   = d_in[12];
  const void* lng  = d_in[13];
  const void* lnb  = d_in[14];
  const void* fw   = d_in[15];
  const void* fb   = d_in[16];
  const void* tw   = d_in[17];
  const void* tb   = d_in[18];
  const void* tmw  = d_in[19];
  const void* tmb  = d_in[20];

  float* wsf = (float*)d_ws;
  int*   wsi = (int*)d_ws;

  hipMemsetAsync(d_ws, 0, (size_t)ZERO_WORDS * 4, stream);
  k_detect<<<1, 256, 0, stream>>>((const unsigned short*)x, wsi + W_FLAG);
  k_deg_doc<<<EBLK + 64, 256, 0, stream>>>(ei + EE, wsi + W_CNT, docf, dw, db,
                                           wsf + W_D, wsi + W_FLAG);
  k_edge2<<<EBLK, 256, 0, stream>>>(ei, ei + EE, wsi + W_CNT, wsf + W_C);
  k_x<<<XBLOCKS, 256, 0, stream>>>(x, pw, wsf + W_C, wsi + W_CNT, wsf + W_SCORE,
                                   wsi + W_HIST, wsf + W_S8, wsi + W_FLAG);
  k_thresh<<<1, 256, 0, stream>>>(wsi + W_HIST, wsi + W_THR, wsf + W_S8, wsf + W_S);
  k_collect<<<NDBLK, 256, 0, stream>>>(wsf + W_SCORE, wsi + W_THR, wsi + W_CANDN,
                                       (unsigned*)(wsi + W_CKEY), wsi + W_CIDX);
  k_top<<<1, 256, 0, stream>>>(wsi + W_CANDN, (const unsigned*)(wsi + W_CKEY),
                               wsi + W_CIDX, x, wsf + W_XT, wsi + W_FLAG);
  k_gru<<<16, 256, 0, stream>>>(wsf + W_XT, h0, wih, whh, bih, bhh, wsf + W_WW, wsi + W_FLAG);
  k_tail<<<1, 256, 0, stream>>>(wsf + W_S, wsf + W_WW, wsf + W_D, gw, gb, lng, lnb,
                                fw, fb, tw, tb, tmw, tmb, d_out, wsi + W_FLAG);
}

// Round 4
// 760.927 us; speedup vs baseline: 1.2631x; 1.0385x over previous
//
#include <hip/hip_runtime.h>
#include <hip/hip_bf16.h>

#define NN    200000
#define EE    3200000
#define DDIMC 768

// ---- small-path workspace layout (word offsets) — ROUND-2 PROVEN ----
#define W_CNT   0          // 200000 i32 (zeroed)
#define W_C     200000     // 200000 f32 (zeroed) -- tacc: sum dis_r*dis_c per row
#define W_HIST  400000     // 65536 i32 (zeroed)
#define W_CANDN 465536     // 1 i32 (zeroed)
#define W_S8    465544     // 8*64 f32 (zeroed)
#define ZERO_WORDS 466056
#define W_FLAG  466056
#define W_THR   466057
#define W_S     466064     // 64 f32
#define W_SCORE 466200     // 200000 f32
#define W_CKEY  666200     // 4096 u32
#define W_CIDX  670296     // 4096 i32
#define W_XT    674392     // 64*64 f32
#define W_WW    678488     // 64*64 f32
#define W_D     682584     // 256 f32

#define CAPL 4096
#define XBLOCKS 1024
#define NDBLK 782
#define EBLK  12500

// ---- helpers ----
__device__ __forceinline__ float ldf(const void* p, int i, int bf) {
  if (bf) return __bfloat162float(((const __hip_bfloat16*)p)[i]);
  return ((const float*)p)[i];
}
__device__ __forceinline__ void stf(void* p, int i, float v, int bf) {
  if (bf) ((__hip_bfloat16*)p)[i] = __float2bfloat16(v);
  else ((float*)p)[i] = v;
}
__device__ __forceinline__ float wsum(float v) {
#pragma unroll
  for (int m = 32; m >= 1; m >>= 1) v += __shfl_xor(v, m, 64);
  return v;
}
__device__ __forceinline__ int wsumi(int v) {
#pragma unroll
  for (int m = 32; m >= 1; m >>= 1) v += __shfl_xor(v, m, 64);
  return v;
}
__device__ __forceinline__ unsigned sortkey(float f) {
  unsigned u = __float_as_uint(f);
  return (u & 0x80000000u) ? ~u : (u | 0x80000000u);
}
// XCD id of the executing workgroup [measured: learn_hip m09]
__device__ __forceinline__ int xcc_id() {
  unsigned x;
  asm volatile("s_getreg_b32 %0, hwreg(HW_REG_XCC_ID)" : "=s"(x));
  return (int)(x & 7u);
}
// XCD-L2-local atomics (workgroup scope -> no cross-XCD coherence bypass;
// correctness: each XCD owns its private replica, folded after dispatch flush)
__device__ __forceinline__ void atomAddWG(int* p, int v) {
  __hip_atomic_fetch_add(p, v, __ATOMIC_RELAXED, __HIP_MEMORY_SCOPE_WORKGROUP);
}
__device__ __forceinline__ void atomAddWG(float* p, float v) {
  __hip_atomic_fetch_add(p, v, __ATOMIC_RELAXED, __HIP_MEMORY_SCOPE_WORKGROUP);
}

// ---- dtype detector: are float tensors stored as bf16? ----
__global__ void k_detect(const unsigned short* x16, int* flag) {
  __shared__ int cnt;
  if (threadIdx.x == 0) cnt = 0;
  __syncthreads();
  int ok = 0;
  for (int k = threadIdx.x; k < 512; k += 256) {
    unsigned short u = x16[2 * k];
    int e = (u >> 7) & 0xFF;
    if (u == 0 || (e >= 100 && e <= 150)) ok++;
  }
  atomicAdd(&cnt, ok);
  __syncthreads();
  if (threadIdx.x == 0) flag[0] = (cnt >= 400) ? 1 : 0;
}

// ================= SMALL PATH (round-2 proven, verbatim) =================

__global__ void k_deg_doc(const int* __restrict__ col, int* __restrict__ cnt,
                          const void* docf, const void* dw, const void* db,
                          float* __restrict__ d, const int* flagp) {
  if (blockIdx.x < EBLK) {
    int i = blockIdx.x * 256 + threadIdx.x;
    if (i < EE) atomicAdd(&cnt[col[i]], 1);
  } else {
    int flag = flagp[0];
    int o = (blockIdx.x - EBLK) * 4 + (threadIdx.x >> 6);
    int lane = threadIdx.x & 63;
    float acc = 0.f;
    for (int k = lane; k < DDIMC; k += 64) acc += ldf(docf, k, flag) * ldf(dw, o * DDIMC + k, flag);
    acc = wsum(acc);
    if (lane == 0) d[o] = fmaxf(acc + ldf(db, o, flag), 0.0f);
  }
}

__global__ void k_edge2(const int* __restrict__ row, const int* __restrict__ col,
                        const int* __restrict__ cnt, float* __restrict__ tacc) {
  int i = blockIdx.x * blockDim.x + threadIdx.x;
  if (i < EE) {
    int r = row[i], cc = col[i];
    float dr = rsqrtf((float)(cnt[r] + 1));
    float dc = rsqrtf((float)(cnt[cc] + 1));
    atomicAdd(&tacc[r], dr * dc);
  }
}

__global__ void k_x(const void* x, const void* pw, const float* __restrict__ tacc,
                    const int* __restrict__ cnt, float* __restrict__ score,
                    int* __restrict__ hist, float* __restrict__ s8, const int* flagp) {
  __shared__ float sred[4][64];
  int flag = flagp[0];
  int t = threadIdx.x;
  int lane = t & 63;
  int w = t >> 6;
  int wid = (blockIdx.x * 256 + t) >> 6;
  int nw = (gridDim.x * 256) >> 6;
  float pwl = ldf(pw, lane, flag);
  float inv = 1.0f / sqrtf(wsum(pwl * pwl));
  float sacc = 0.f;
  for (int r = wid; r < NN; r += nw) {
    float xv = ldf(x, r * 64 + lane, flag);
    float dot = wsum(xv * pwl);
    float cr = tacc[r] + 1.0f / (float)(cnt[r] + 1);
    sacc += cr * xv;
    if (lane == 0) {
      float sc = dot * inv;
      score[r] = sc;
      atomicAdd(&hist[sortkey(sc) >> 16], 1);
    }
  }
  sred[w][lane] = sacc;
  __syncthreads();
  if (w == 0)
    atomicAdd(&s8[(blockIdx.x & 7) * 64 + lane],
              sred[0][lane] + sred[1][lane] + sred[2][lane] + sred[3][lane]);
}

// ================= BIG PATH (XCD-local L2 atomics, per-XCD replicas) =================

__global__ void k_deg_doc_x(const int* __restrict__ col, int* __restrict__ cnt8,
                            const void* docf, const void* dw, const void* db,
                            float* __restrict__ d, const int* flagp) {
  if (blockIdx.x < EBLK) {
    int i = blockIdx.x * 256 + threadIdx.x;
    int xb = xcc_id() * NN;
    if (i < EE) atomAddWG(&cnt8[xb + col[i]], 1);
  } else {
    int flag = flagp[0];
    int o = (blockIdx.x - EBLK) * 4 + (threadIdx.x >> 6);
    int lane = threadIdx.x & 63;
    float acc = 0.f;
    for (int k = lane; k < DDIMC; k += 64) acc += ldf(docf, k, flag) * ldf(dw, o * DDIMC + k, flag);
    acc = wsum(acc);
    if (lane == 0) d[o] = fmaxf(acc + ldf(db, o, flag), 0.0f);
  }
}

__global__ void k_fold_x(const int* __restrict__ cnt8, float* __restrict__ dis) {
  int i = blockIdx.x * 256 + threadIdx.x;
  if (i < NN) {
    int deg = 1;
#pragma unroll
    for (int r = 0; r < 8; r++) deg += cnt8[r * NN + i];
    dis[i] = rsqrtf((float)deg);
  }
}

__global__ void k_edge2_x(const int* __restrict__ row, const int* __restrict__ col,
                          const float* __restrict__ dis, float* __restrict__ tacc8) {
  int i = blockIdx.x * blockDim.x + threadIdx.x;
  if (i < EE) {
    int r = row[i], cc = col[i];
    int xb = xcc_id() * NN;
    atomAddWG(&tacc8[xb + r], dis[r] * dis[cc]);
  }
}

__global__ void k_x_x(const void* x, const void* pw, const float* __restrict__ tacc8,
                      const float* __restrict__ dis, float* __restrict__ score,
                      int* __restrict__ hist, float* __restrict__ s8, const int* flagp) {
  __shared__ float sred[4][64];
  int flag = flagp[0];
  int t = threadIdx.x;
  int lane = t & 63;
  int w = t >> 6;
  int wid = (blockIdx.x * 256 + t) >> 6;
  int nw = (gridDim.x * 256) >> 6;
  float pwl = ldf(pw, lane, flag);
  float inv = 1.0f / sqrtf(wsum(pwl * pwl));
  float sacc = 0.f;
  for (int r = wid; r < NN; r += nw) {
    float xv = ldf(x, r * 64 + lane, flag);
    float dot = wsum(xv * pwl);
    float dv = dis[r];
    float cr = dv * dv;
#pragma unroll
    for (int rr = 0; rr < 8; rr++) cr += tacc8[rr * NN + r];
    sacc += cr * xv;
    if (lane == 0) {
      float sc = dot * inv;
      score[r] = sc;
      atomicAdd(&hist[sortkey(sc) >> 16], 1);
    }
  }
  sred[w][lane] = sacc;
  __syncthreads();
  if (w == 0)
    atomicAdd(&s8[(blockIdx.x & 7) * 64 + lane],
              sred[0][lane] + sred[1][lane] + sred[2][lane] + sred[3][lane]);
}

// ================= SHARED TAIL (round-2 proven, verbatim) =================

__global__ void k_thresh(const int* __restrict__ hist, int* __restrict__ thrB,
                         const float* __restrict__ s8, float* __restrict__ svec) {
  __shared__ int part[256];
  __shared__ int segl[256];
  __shared__ int res2[2];
  int t = threadIdx.x, w = t >> 6, lane = t & 63;
  if (t < 64) {
    float a = 0.f;
    for (int r = 0; r < 8; r++) a += s8[r * 64 + t];
    svec[t] = a;
  }
  for (int m = w; m < 256; m += 4) {
    const int* hb = &hist[m * 256];
    int a = hb[lane] + hb[lane + 64] + hb[lane + 128] + hb[lane + 192];
    a = wsumi(a);
    if (lane == 0) part[m] = a;
  }
  __syncthreads();
  if (t == 0) {
    int acc = 0, seg = 0, above = 0;
    for (int b = 255; b >= 0; b--) {
      if (acc + part[b] >= 64) { seg = b; above = acc; break; }
      acc += part[b];
    }
    res2[0] = seg; res2[1] = above;
  }
  __syncthreads();
  segl[t] = hist[res2[0] * 256 + t];
  __syncthreads();
  if (t == 0) {
    int acc = res2[1], B = res2[0] * 256;
    for (int j = 255; j >= 0; j--) {
      acc += segl[j];
      if (acc >= 64) { B = res2[0] * 256 + j; break; }
    }
    thrB[0] = B;
  }
}

__global__ void k_collect(const float* __restrict__ score, const int* __restrict__ thrB,
                          int* __restrict__ candn, unsigned* __restrict__ ckey,
                          int* __restrict__ cidx) {
  int i = blockIdx.x * blockDim.x + threadIdx.x;
  if (i >= NN) return;
  unsigned u = sortkey(score[i]);
  if ((int)(u >> 16) >= thrB[0]) {
    int p = atomicAdd(candn, 1);
    if (p < CAPL) { ckey[p] = u; cidx[p] = i; }
  }
}

__global__ void k_top(const int* __restrict__ candn, const unsigned* __restrict__ ckey,
                      const int* __restrict__ cidx, const void* x,
                      float* __restrict__ xt, const int* flagp) {
  __shared__ unsigned long long keys[CAPL];
  __shared__ int perm[64];
  __shared__ float ts[64];
  int flag = flagp[0];
  int t = threadIdx.x;
  int M = candn[0];
  if (M > CAPL) M = CAPL;
  for (int j = t; j < M; j += 256)
    keys[j] = (((unsigned long long)ckey[j]) << 32) |
              (unsigned long long)(0xFFFFFFFFu - (unsigned)cidx[j]);
  __syncthreads();
  for (int j = t; j < M; j += 256) {
    unsigned long long k = keys[j];
    int rank = 0;
    for (int i = 0; i < M; i++) rank += (keys[i] > k) ? 1 : 0;
    if (rank < 64) {
      unsigned ku = (unsigned)(k >> 32);
      unsigned idx = 0xFFFFFFFFu - (unsigned)(k & 0xFFFFFFFFu);
      perm[rank] = (int)idx;
      unsigned bits = (ku & 0x80000000u) ? (ku ^ 0x80000000u) : ~ku;
      ts[rank] = tanhf(__uint_as_float(bits));
    }
  }
  __syncthreads();
  for (int q = t; q < 4096; q += 256) {
    int j = q >> 6, f = q & 63;
    xt[q] = ldf(x, perm[j] * 64 + f, flag) * ts[j];
  }
}

__global__ void k_gru(const float* __restrict__ xt, const void* h0g, const void* wihg,
                      const void* whhg, const void* bihg, const void* bhhg,
                      float* __restrict__ Wout, const int* flagp) {
  __shared__ float wbuf[192 * 64];
  __shared__ float xtr[256];
  __shared__ float h0r[256];
  int flag = flagp[0];
  int t = threadIdx.x;
  int j0 = blockIdx.x * 4;
  { int jj = t >> 6, f = t & 63;
    xtr[t] = xt[(j0 + jj) * 64 + f];
    h0r[t] = ldf(h0g, (j0 + jj) * 64 + f, flag); }
  for (int k = t; k < 12288; k += 256) { int f = k / 192, o = k % 192; wbuf[f * 192 + o] = ldf(wihg, o * 64 + f, flag); }
  __syncthreads();
  int jl = t >> 6, c2 = t & 63;
  float xr = 0, xz = 0, xn = 0;
  for (int f = 0; f < 64; f++) {
    float xv = xtr[jl * 64 + f];
    const float* wr = &wbuf[f * 192];
    xr += xv * wr[c2]; xz += xv * wr[64 + c2]; xn += xv * wr[128 + c2];
  }
  __syncthreads();
  for (int k = t; k < 12288; k += 256) { int f = k / 192, o = k % 192; wbuf[f * 192 + o] = ldf(whhg, o * 64 + f, flag); }
  __syncthreads();
  float hr = 0, hz = 0, hn = 0;
  for (int f = 0; f < 64; f++) {
    float hv = h0r[jl * 64 + f];
    const float* wr = &wbuf[f * 192];
    hr += hv * wr[c2]; hz += hv * wr[64 + c2]; hn += hv * wr[128 + c2];
  }
  xr += ldf(bihg, c2, flag); xz += ldf(bihg, 64 + c2, flag); xn += ldf(bihg, 128 + c2, flag);
  hr += ldf(bhhg, c2, flag); hz += ldf(bhhg, 64 + c2, flag); hn += ldf(bhhg, 128 + c2, flag);
  float rg = 1.f / (1.f + expf(-(xr + hr)));
  float zg = 1.f / (1.f + expf(-(xz + hz)));
  float nc = tanhf(xn + rg * hn);
  Wout[(j0 + jl) * 64 + c2] = (1.f - zg) * nc + zg * h0r[jl * 64 + c2];
}

__global__ void k_tail(const float* __restrict__ svec, const float* __restrict__ Wm,
                       const float* __restrict__ d, const void* gw, const void* gb,
                       const void* lng, const void* lnb, const void* fw, const void* fb,
                       const void* tw, const void* tb, const void* tmw, const void* tmb,
                       void* out, const int* flagp) {
  __shared__ float pooled[64];
  __shared__ float lnv[512];
  __shared__ float red[256];
  __shared__ float stats[2];
  __shared__ float h1s[256];
  int flag = flagp[0];
  int t = threadIdx.x;
  if (t < 64) {
    float a = 0.f;
    for (int f = 0; f < 64; f++) a += svec[f] * Wm[f * 64 + t];
    pooled[t] = a * (1.0f / (float)NN);
  }
  __syncthreads();
  float v0 = 0;
  { float a = 0.f;
    for (int c2 = 0; c2 < 64; c2++) a += pooled[c2] * ldf(gw, t * 64 + c2, flag);
    v0 = a + ldf(gb, t, flag); }
  float v1 = d[t];
  red[t] = v0 + v1; __syncthreads();
  for (int s = 128; s > 0; s >>= 1) { if (t < s) red[t] += red[t + s]; __syncthreads(); }
  if (t == 0) stats[0] = red[0];
  __syncthreads();
  red[t] = v0 * v0 + v1 * v1; __syncthreads();
  for (int s = 128; s > 0; s >>= 1) { if (t < s) red[t] += red[t + s]; __syncthreads(); }
  if (t == 0) stats[1] = red[0];
  __syncthreads();
  float mu = stats[0] * (1.f / 512.f);
  float var = stats[1] * (1.f / 512.f) - mu * mu;
  float istd = rsqrtf(var + 1e-5f);
  lnv[t]       = (v0 - mu) * istd * ldf(lng, t, flag)       + ldf(lnb, t, flag);
  lnv[t + 256] = (v1 - mu) * istd * ldf(lng, t + 256, flag) + ldf(lnb, t + 256, flag);
  __syncthreads();
  int w = t >> 6, lane = t & 63;
  for (int o = w; o < 256; o += 4) {
    float acc = 0.f;
    for (int k = lane; k < 512; k += 64) acc += lnv[k] * ldf(fw, o * 512 + k, flag);
    acc = wsum(acc);
    if (lane == 0) h1s[o] = fmaxf(acc + ldf(fb, o, flag), 0.0f);
  }
  __syncthreads();
  for (int o = w; o < 17; o += 4) {
    float acc = 0.f;
    if (o < 16) { for (int k = lane; k < 256; k += 64) acc += h1s[k] * ldf(tw, o * 256 + k, flag); }
    else        { for (int k = lane; k < 256; k += 64) acc += h1s[k] * ldf(tmw, k, flag); }
    acc = wsum(acc);
    if (lane == 0) {
      float bias = (o < 16) ? ldf(tb, o, flag) : ldf(tmb, 0, flag);
      stf(out, o, acc + bias, flag);
    }
  }
}

extern "C" void kernel_launch(void* const* d_in, const int* in_sizes, int n_in,
                              void* d_out, int out_size, void* d_ws, size_t ws_size,
                              hipStream_t stream) {
  const void* x    = d_in[0];
  const int*  ei   = (const int*)d_in[1];
  const void* docf = d_in[2];
  const void* pw   = d_in[3];
  const void* h0   = d_in[4];
  const void* wih  = d_in[5];
  const void* whh  = d_in[6];
  const void* bih  = d_in[7];
  const void* bhh  = d_in[8];
  const void* gw   = d_in[9];
  const void* gb   = d_in[10];
  const void* dw   = d_in[11];
  const void* db   = d_in[12];
  const void* lng  = d_in[13];
  const void* lnb  = d_in[14];
  const void* fw   = d_in[15];
  const void* fb   = d_in[16];
  const void* tw   = d_in[17];
  const void* tb   = d_in[18];
  const void* tmw  = d_in[19];
  const void* tmb  = d_in[20];

  float* wsf = (float*)d_ws;
  int*   wsi = (int*)d_ws;

  // big-path layout (words)
  const size_t B_CNT8 = 0;
  const size_t B_TACC8 = (size_t)8 * NN;
  const size_t B_HIST  = (size_t)16 * NN;
  const size_t B_CANDN = B_HIST + 65536;
  const size_t B_S8    = B_CANDN + 8;
  const size_t B_ZERO  = B_S8 + 512;
  const size_t B_FLAG  = B_ZERO;
  const size_t B_THR   = B_FLAG + 8;
  const size_t B_SV    = B_THR + 8;
  const size_t B_D     = B_SV + 64;
  const size_t B_DIS   = B_D + 256;
  const size_t B_SCORE = B_DIS + NN;
  const size_t B_CKEY  = B_SCORE + NN;
  const size_t B_CIDX  = B_CKEY + 4096;
  const size_t B_XT    = B_CIDX + 4096;
  const size_t B_WW    = B_XT + 4096;
  const size_t B_END   = B_WW + 4096;

  bool big = (ws_size / 4) >= B_END;

  if (big) {
    hipMemsetAsync(d_ws, 0, B_ZERO * 4, stream);
    k_detect<<<1, 256, 0, stream>>>((const unsigned short*)x, wsi + B_FLAG);
    k_deg_doc_x<<<EBLK + 64, 256, 0, stream>>>(ei + EE, wsi + B_CNT8, docf, dw, db,
                                               wsf + B_D, wsi + B_FLAG);
    k_fold_x<<<NDBLK, 256, 0, stream>>>(wsi + B_CNT8, wsf + B_DIS);
    k_edge2_x<<<EBLK, 256, 0, stream>>>(ei, ei + EE, wsf + B_DIS, wsf + B_TACC8);
    k_x_x<<<XBLOCKS, 256, 0, stream>>>(x, pw, wsf + B_TACC8, wsf + B_DIS,
                                       wsf + B_SCORE, wsi + B_HIST, wsf + B_S8, wsi + B_FLAG);
    k_thresh<<<1, 256, 0, stream>>>(wsi + B_HIST, wsi + B_THR, wsf + B_S8, wsf + B_SV);
    k_collect<<<NDBLK, 256, 0, stream>>>(wsf + B_SCORE, wsi + B_THR, wsi + B_CANDN,
                                         (unsigned*)(wsi + B_CKEY), wsi + B_CIDX);
    k_top<<<1, 256, 0, stream>>>(wsi + B_CANDN, (const unsigned*)(wsi + B_CKEY),
                                 wsi + B_CIDX, x, wsf + B_XT, wsi + B_FLAG);
    k_gru<<<16, 256, 0, stream>>>(wsf + B_XT, h0, wih, whh, bih, bhh, wsf + B_WW, wsi + B_FLAG);
    k_tail<<<1, 256, 0, stream>>>(wsf + B_SV, wsf + B_WW, wsf + B_D, gw, gb, lng, lnb,
                                  fw, fb, tw, tb, tmw, tmb, d_out, wsi + B_FLAG);
  } else {
    hipMemsetAsync(d_ws, 0, (size_t)ZERO_WORDS * 4, stream);
    k_detect<<<1, 256, 0, stream>>>((const unsigned short*)x, wsi + W_FLAG);
    k_deg_doc<<<EBLK + 64, 256, 0, stream>>>(ei + EE, wsi + W_CNT, docf, dw, db,
                                             wsf + W_D, wsi + W_FLAG);
    k_edge2<<<EBLK, 256, 0, stream>>>(ei, ei + EE, wsi + W_CNT, wsf + W_C);
    k_x<<<XBLOCKS, 256, 0, stream>>>(x, pw, wsf + W_C, wsi + W_CNT, wsf + W_SCORE,
                                     wsi + W_HIST, wsf + W_S8, wsi + W_FLAG);
    k_thresh<<<1, 256, 0, stream>>>(wsi + W_HIST, wsi + W_THR, wsf + W_S8, wsf + W_S);
    k_collect<<<NDBLK, 256, 0, stream>>>(wsf + W_SCORE, wsi + W_THR, wsi + W_CANDN,
                                         (unsigned*)(wsi + W_CKEY), wsi + W_CIDX);
    k_top<<<1, 256, 0, stream>>>(wsi + W_CANDN, (const unsigned*)(wsi + W_CKEY),
                                 wsi + W_CIDX, x, wsf + W_XT, wsi + W_FLAG);
    k_gru<<<16, 256, 0, stream>>>(wsf + W_XT, h0, wih, whh, bih, bhh, wsf + W_WW, wsi + W_FLAG);
    k_tail<<<1, 256, 0, stream>>>(wsf + W_S, wsf + W_WW, wsf + W_D, gw, gb, lng, lnb,
                                  fw, fb, tw, tb, tmw, tmb, d_out, wsi + W_FLAG);
  }
}

// Round 6
// 755.673 us; speedup vs baseline: 1.2719x; 1.0070x over previous
//
#include <hip/hip_runtime.h>
#include <hip/hip_bf16.h>

#define NN    200000
#define EE    3200000
#define DDIMC 768

#define NB    25        // node buckets
#define BSH   13
#define BSZ   8192      // nodes per bucket -> 32KB LDS histogram
#define CC    12        // edge chunks per bucket (compile-time)
#define NI4   800000    // EE/4 int4s
#define BW4   2048      // int4 window (32KB) -> loose-lockstep L2 reuse
#define PARTW (NB * CC * BSZ)   // 2,457,600 words

#define NDBLK 782       // ceil(NN/256)
#define XBLOCKS 1024
#define EBLK  12500
#define CAPL  4096

// ---- workspace layout (word offsets); total 3,140,376 words = 12.6MB (< proven 14.7MB) ----
#define P_PART  0
#define P_TACC  PARTW                    // NN f32 (zeroed)
#define P_HIST  (P_TACC + NN)            // 65536 i32 (zeroed)
#define P_CANDN (P_HIST + 65536)         // 8 (zeroed)
#define P_S8    (P_CANDN + 8)            // 512 (zeroed)
#define P_FLAG  (P_S8 + 512)
#define P_THR   (P_FLAG + 8)
#define P_SV    (P_THR + 8)
#define P_D     (P_SV + 64)
#define P_DIS   (P_D + 256)
#define P_SCORE (P_DIS + NN)
#define P_CKEY  (P_SCORE + NN)
#define P_CIDX  (P_CKEY + 4096)
#define P_XT    (P_CIDX + 4096)
#define P_WW    (P_XT + 4096)
#define ZERO_LEN (NN + 65536 + 8 + 512)  // from P_TACC

// ---- helpers (round-4 proven) ----
__device__ __forceinline__ float ldf(const void* p, int i, int bf) {
  if (bf) return __bfloat162float(((const __hip_bfloat16*)p)[i]);
  return ((const float*)p)[i];
}
__device__ __forceinline__ void stf(void* p, int i, float v, int bf) {
  if (bf) ((__hip_bfloat16*)p)[i] = __float2bfloat16(v);
  else ((float*)p)[i] = v;
}
__device__ __forceinline__ float wsum(float v) {
#pragma unroll
  for (int m = 32; m >= 1; m >>= 1) v += __shfl_xor(v, m, 64);
  return v;
}
__device__ __forceinline__ int wsumi(int v) {
#pragma unroll
  for (int m = 32; m >= 1; m >>= 1) v += __shfl_xor(v, m, 64);
  return v;
}
__device__ __forceinline__ unsigned sortkey(float f) {
  unsigned u = __float_as_uint(f);
  return (u & 0x80000000u) ? ~u : (u | 0x80000000u);
}

// ---- dtype detector (proven) ----
__global__ void k_detect(const unsigned short* x16, int* flag) {
  __shared__ int cnt;
  if (threadIdx.x == 0) cnt = 0;
  __syncthreads();
  int ok = 0;
  for (int k = threadIdx.x; k < 512; k += 256) {
    unsigned short u = x16[2 * k];
    int e = (u >> 7) & 0xFF;
    if (u == 0 || (e >= 100 && e <= 150)) ok++;
  }
  atomicAdd(&cnt, ok);
  __syncthreads();
  if (threadIdx.x == 0) flag[0] = (cnt >= 400) ? 1 : 0;
}

// ---- NEW (this round's single experiment): bucketed degree histogram, 32KB LDS ----
__global__ void k_hcol(const int* __restrict__ col, int* __restrict__ part) {
  __shared__ int lh[BSZ];
  int t = threadIdx.x;
  int b = blockIdx.x / CC, j = blockIdx.x % CC;
  for (int k = t; k < BSZ; k += 256) lh[k] = 0;
  __syncthreads();
  int base = b << BSH;
  const int4* c4 = (const int4*)col;
  for (int w0 = j * BW4; w0 < NI4; w0 += CC * BW4) {
    int end = w0 + BW4; if (end > NI4) end = NI4;
    for (int i = w0 + t; i < end; i += 256) {
      int4 v = c4[i];
      int a0 = v.x - base, a1 = v.y - base, a2 = v.z - base, a3 = v.w - base;
      if ((unsigned)a0 < (unsigned)BSZ) atomicAdd(&lh[a0], 1);
      if ((unsigned)a1 < (unsigned)BSZ) atomicAdd(&lh[a1], 1);
      if ((unsigned)a2 < (unsigned)BSZ) atomicAdd(&lh[a2], 1);
      if ((unsigned)a3 < (unsigned)BSZ) atomicAdd(&lh[a3], 1);
    }
  }
  __syncthreads();
  int* dst = part + (size_t)blockIdx.x * BSZ;
  for (int k = t; k < BSZ; k += 256) dst[k] = lh[k];
}

// ---- reduce partials -> dis; doc matvec on extra blocks (both pieces proven patterns) ----
__global__ void k_redA(const int* __restrict__ part, float* __restrict__ dis,
                       const void* docf, const void* dw, const void* db,
                       float* __restrict__ d, const int* flagp) {
  if (blockIdx.x < NDBLK) {
    int i = blockIdx.x * 256 + threadIdx.x;
    if (i < NN) {
      int b = i >> BSH, k = i & (BSZ - 1);
      const int* p = part + (size_t)b * CC * BSZ + k;
      int deg = 1;
#pragma unroll
      for (int j = 0; j < CC; j++) deg += p[(size_t)j * BSZ];
      dis[i] = rsqrtf((float)deg);
    }
  } else {
    int flag = flagp[0];
    int o = (blockIdx.x - NDBLK) * 4 + (threadIdx.x >> 6);
    int lane = threadIdx.x & 63;
    float acc = 0.f;
    for (int k = lane; k < DDIMC; k += 64) acc += ldf(docf, k, flag) * ldf(dw, o * DDIMC + k, flag);
    acc = wsum(acc);
    if (lane == 0) d[o] = fmaxf(acc + ldf(db, o, flag), 0.0f);
  }
}

// ---- tacc pass: proven global-atomic form (round 4, single replica) ----
__global__ void k_edge2(const int* __restrict__ row, const int* __restrict__ col,
                        const float* __restrict__ dis, float* __restrict__ tacc) {
  int i = blockIdx.x * blockDim.x + threadIdx.x;
  if (i < EE) {
    int r = row[i], cc = col[i];
    atomicAdd(&tacc[r], dis[r] * dis[cc]);
  }
}

// ---- fused x pass (round-2 proven structure; cr = tacc + dis^2) ----
__global__ void k_x(const void* x, const void* pw, const float* __restrict__ tacc,
                    const float* __restrict__ dis, float* __restrict__ score,
                    int* __restrict__ hist, float* __restrict__ s8, const int* flagp) {
  __shared__ float sred[4][64];
  int flag = flagp[0];
  int t = threadIdx.x;
  int lane = t & 63;
  int w = t >> 6;
  int wid = (blockIdx.x * 256 + t) >> 6;
  int nw = (gridDim.x * 256) >> 6;
  float pwl = ldf(pw, lane, flag);
  float inv = 1.0f / sqrtf(wsum(pwl * pwl));
  float sacc = 0.f;
  for (int r = wid; r < NN; r += nw) {
    float xv = ldf(x, r * 64 + lane, flag);
    float dot = wsum(xv * pwl);
    float dv = dis[r];
    float cr = tacc[r] + dv * dv;
    sacc += cr * xv;
    if (lane == 0) {
      float sc = dot * inv;
      score[r] = sc;
      atomicAdd(&hist[sortkey(sc) >> 16], 1);
    }
  }
  sred[w][lane] = sacc;
  __syncthreads();
  if (w == 0)
    atomicAdd(&s8[(blockIdx.x & 7) * 64 + lane],
              sred[0][lane] + sred[1][lane] + sred[2][lane] + sred[3][lane]);
}

// ---- threshold (proven) ----
__global__ void k_thresh(const int* __restrict__ hist, int* __restrict__ thrB,
                         const float* __restrict__ s8, float* __restrict__ svec) {
  __shared__ int part[256];
  __shared__ int segl[256];
  __shared__ int res2[2];
  int t = threadIdx.x, w = t >> 6, lane = t & 63;
  if (t < 64) {
    float a = 0.f;
    for (int r = 0; r < 8; r++) a += s8[r * 64 + t];
    svec[t] = a;
  }
  for (int m = w; m < 256; m += 4) {
    const int* hb = &hist[m * 256];
    int a = hb[lane] + hb[lane + 64] + hb[lane + 128] + hb[lane + 192];
    a = wsumi(a);
    if (lane == 0) part[m] = a;
  }
  __syncthreads();
  if (t == 0) {
    int acc = 0, seg = 0, above = 0;
    for (int b = 255; b >= 0; b--) {
      if (acc + part[b] >= 64) { seg = b; above = acc; break; }
      acc += part[b];
    }
    res2[0] = seg; res2[1] = above;
  }
  __syncthreads();
  segl[t] = hist[res2[0] * 256 + t];
  __syncthreads();
  if (t == 0) {
    int acc = res2[1], B = res2[0] * 256;
    for (int j = 255; j >= 0; j--) {
      acc += segl[j];
      if (acc >= 64) { B = res2[0] * 256 + j; break; }
    }
    thrB[0] = B;
  }
}

// ---- collect (proven) ----
__global__ void k_collect(const float* __restrict__ score, const int* __restrict__ thrB,
                          int* __restrict__ candn, unsigned* __restrict__ ckey,
                          int* __restrict__ cidx) {
  int i = blockIdx.x * blockDim.x + threadIdx.x;
  if (i >= NN) return;
  unsigned u = sortkey(score[i]);
  if ((int)(u >> 16) >= thrB[0]) {
    int p = atomicAdd(candn, 1);
    if (p < CAPL) { ckey[p] = u; cidx[p] = i; }
  }
}

// ---- top-64 (proven) ----
__global__ void k_top(const int* __restrict__ candn, const unsigned* __restrict__ ckey,
                      const int* __restrict__ cidx, const void* x,
                      float* __restrict__ xt, const int* flagp) {
  __shared__ unsigned long long keys[CAPL];
  __shared__ int perm[64];
  __shared__ float ts[64];
  int flag = flagp[0];
  int t = threadIdx.x;
  int M = candn[0];
  if (M > CAPL) M = CAPL;
  for (int j = t; j < M; j += 256)
    keys[j] = (((unsigned long long)ckey[j]) << 32) |
              (unsigned long long)(0xFFFFFFFFu - (unsigned)cidx[j]);
  __syncthreads();
  for (int j = t; j < M; j += 256) {
    unsigned long long k = keys[j];
    int rank = 0;
    for (int i = 0; i < M; i++) rank += (keys[i] > k) ? 1 : 0;
    if (rank < 64) {
      unsigned ku = (unsigned)(k >> 32);
      unsigned idx = 0xFFFFFFFFu - (unsigned)(k & 0xFFFFFFFFu);
      perm[rank] = (int)idx;
      unsigned bits = (ku & 0x80000000u) ? (ku ^ 0x80000000u) : ~ku;
      ts[rank] = tanhf(__uint_as_float(bits));
    }
  }
  __syncthreads();
  for (int q = t; q < 4096; q += 256) {
    int j = q >> 6, f = q & 63;
    xt[q] = ldf(x, perm[j] * 64 + f, flag) * ts[j];
  }
}

// ---- GRU (proven) ----
__global__ void k_gru(const float* __restrict__ xt, const void* h0g, const void* wihg,
                      const void* whhg, const void* bihg, const void* bhhg,
                      float* __restrict__ Wout, const int* flagp) {
  __shared__ float wbuf[192 * 64];
  __shared__ float xtr[256];
  __shared__ float h0r[256];
  int flag = flagp[0];
  int t = threadIdx.x;
  int j0 = blockIdx.x * 4;
  { int jj = t >> 6, f = t & 63;
    xtr[t] = xt[(j0 + jj) * 64 + f];
    h0r[t] = ldf(h0g, (j0 + jj) * 64 + f, flag); }
  for (int k = t; k < 12288; k += 256) { int f = k / 192, o = k % 192; wbuf[f * 192 + o] = ldf(wihg, o * 64 + f, flag); }
  __syncthreads();
  int jl = t >> 6, c2 = t & 63;
  float xr = 0, xz = 0, xn = 0;
  for (int f = 0; f < 64; f++) {
    float xv = xtr[jl * 64 + f];
    const float* wr = &wbuf[f * 192];
    xr += xv * wr[c2]; xz += xv * wr[64 + c2]; xn += xv * wr[128 + c2];
  }
  __syncthreads();
  for (int k = t; k < 12288; k += 256) { int f = k / 192, o = k % 192; wbuf[f * 192 + o] = ldf(whhg, o * 64 + f, flag); }
  __syncthreads();
  float hr = 0, hz = 0, hn = 0;
  for (int f = 0; f < 64; f++) {
    float hv = h0r[jl * 64 + f];
    const float* wr = &wbuf[f * 192];
    hr += hv * wr[c2]; hz += hv * wr[64 + c2]; hn += hv * wr[128 + c2];
  }
  xr += ldf(bihg, c2, flag); xz += ldf(bihg, 64 + c2, flag); xn += ldf(bihg, 128 + c2, flag);
  hr += ldf(bhhg, c2, flag); hz += ldf(bhhg, 64 + c2, flag); hn += ldf(bhhg, 128 + c2, flag);
  float rg = 1.f / (1.f + expf(-(xr + hr)));
  float zg = 1.f / (1.f + expf(-(xz + hz)));
  float nc = tanhf(xn + rg * hn);
  Wout[(j0 + jl) * 64 + c2] = (1.f - zg) * nc + zg * h0r[jl * 64 + c2];
}

// ---- tail (proven) ----
__global__ void k_tail(const float* __restrict__ svec, const float* __restrict__ Wm,
                       const float* __restrict__ d, const void* gw, const void* gb,
                       const void* lng, const void* lnb, const void* fw, const void* fb,
                       const void* tw, const void* tb, const void* tmw, const void* tmb,
                       void* out, const int* flagp) {
  __shared__ float pooled[64];
  __shared__ float lnv[512];
  __shared__ float red[256];
  __shared__ float stats[2];
  __shared__ float h1s[256];
  int flag = flagp[0];
  int t = threadIdx.x;
  if (t < 64) {
    float a = 0.f;
    for (int f = 0; f < 64; f++) a += svec[f] * Wm[f * 64 + t];
    pooled[t] = a * (1.0f / (float)NN);
  }
  __syncthreads();
  float v0 = 0;
  { float a = 0.f;
    for (int c2 = 0; c2 < 64; c2++) a += pooled[c2] * ldf(gw, t * 64 + c2, flag);
    v0 = a + ldf(gb, t, flag); }
  float v1 = d[t];
  red[t] = v0 + v1; __syncthreads();
  for (int s = 128; s > 0; s >>= 1) { if (t < s) red[t] += red[t + s]; __syncthreads(); }
  if (t == 0) stats[0] = red[0];
  __syncthreads();
  red[t] = v0 * v0 + v1 * v1; __syncthreads();
  for (int s = 128; s > 0; s >>= 1) { if (t < s) red[t] += red[t + s]; __syncthreads(); }
  if (t == 0) stats[1] = red[0];
  __syncthreads();
  float mu = stats[0] * (1.f / 512.f);
  float var = stats[1] * (1.f / 512.f) - mu * mu;
  float istd = rsqrtf(var + 1e-5f);
  lnv[t]       = (v0 - mu) * istd * ldf(lng, t, flag)       + ldf(lnb, t, flag);
  lnv[t + 256] = (v1 - mu) * istd * ldf(lng, t + 256, flag) + ldf(lnb, t + 256, flag);
  __syncthreads();
  int w = t >> 6, lane = t & 63;
  for (int o = w; o < 256; o += 4) {
    float acc = 0.f;
    for (int k = lane; k < 512; k += 64) acc += lnv[k] * ldf(fw, o * 512 + k, flag);
    acc = wsum(acc);
    if (lane == 0) h1s[o] = fmaxf(acc + ldf(fb, o, flag), 0.0f);
  }
  __syncthreads();
  for (int o = w; o < 17; o += 4) {
    float acc = 0.f;
    if (o < 16) { for (int k = lane; k < 256; k += 64) acc += h1s[k] * ldf(tw, o * 256 + k, flag); }
    else        { for (int k = lane; k < 256; k += 64) acc += h1s[k] * ldf(tmw, k, flag); }
    acc = wsum(acc);
    if (lane == 0) {
      float bias = (o < 16) ? ldf(tb, o, flag) : ldf(tmb, 0, flag);
      stf(out, o, acc + bias, flag);
    }
  }
}

extern "C" void kernel_launch(void* const* d_in, const int* in_sizes, int n_in,
                              void* d_out, int out_size, void* d_ws, size_t ws_size,
                              hipStream_t stream) {
  const void* x    = d_in[0];
  const int*  ei   = (const int*)d_in[1];
  const void* docf = d_in[2];
  const void* pw   = d_in[3];
  const void* h0   = d_in[4];
  const void* wih  = d_in[5];
  const void* whh  = d_in[6];
  const void* bih  = d_in[7];
  const void* bhh  = d_in[8];
  const void* gw   = d_in[9];
  const void* gb   = d_in[10];
  const void* dw   = d_in[11];
  const void* db   = d_in[12];
  const void* lng  = d_in[13];
  const void* lnb  = d_in[14];
  const void* fw   = d_in[15];
  const void* fb   = d_in[16];
  const void* tw   = d_in[17];
  const void* tb   = d_in[18];
  const void* tmw  = d_in[19];
  const void* tmb  = d_in[20];

  const int* row = ei;
  const int* col = ei + EE;

  float* wsf = (float*)d_ws;
  int*   wsi = (int*)d_ws;

  hipMemsetAsync(wsi + P_TACC, 0, (size_t)ZERO_LEN * 4, stream);
  k_detect<<<1, 256, 0, stream>>>((const unsigned short*)x, wsi + P_FLAG);
  k_hcol<<<NB * CC, 256, 0, stream>>>(col, wsi + P_PART);
  k_redA<<<NDBLK + 64, 256, 0, stream>>>(wsi + P_PART, wsf + P_DIS, docf, dw, db,
                                         wsf + P_D, wsi + P_FLAG);
  k_edge2<<<EBLK, 256, 0, stream>>>(row, col, wsf + P_DIS, wsf + P_TACC);
  k_x<<<XBLOCKS, 256, 0, stream>>>(x, pw, wsf + P_TACC, wsf + P_DIS, wsf + P_SCORE,
                                   wsi + P_HIST, wsf + P_S8, wsi + P_FLAG);
  k_thresh<<<1, 256, 0, stream>>>(wsi + P_HIST, wsi + P_THR, wsf + P_S8, wsf + P_SV);
  k_collect<<<NDBLK, 256, 0, stream>>>(wsf + P_SCORE, wsi + P_THR, wsi + P_CANDN,
                                       (unsigned*)(wsi + P_CKEY), wsi + P_CIDX);
  k_top<<<1, 256, 0, stream>>>(wsi + P_CANDN, (const unsigned*)(wsi + P_CKEY),
                               wsi + P_CIDX, x, wsf + P_XT, wsi + P_FLAG);
  k_gru<<<16, 256, 0, stream>>>(wsf + P_XT, h0, wih, whh, bih, bhh, wsf + P_WW, wsi + P_FLAG);
  k_tail<<<1, 256, 0, stream>>>(wsf + P_SV, wsf + P_WW, wsf + P_D, gw, gb, lng, lnb,
                                fw, fb, tw, tb, tmw, tmb, d_out, wsi + P_FLAG);
}

// Round 7
// 694.202 us; speedup vs baseline: 1.3845x; 1.0885x over previous
//
#include <hip/hip_runtime.h>
#include <hip/hip_bf16.h>

#define NN    200000
#define EE    3200000
#define DDIMC 768

#define NB    25        // node buckets
#define BSH   13
#define BSZ   8192      // nodes per bucket -> 32KB LDS histogram
#define CC    12        // edge chunks per bucket
#define NI4   800000    // EE/4 int4s
#define BW4   2048      // int4 window (32KB)
#define PARTW (NB * CC * BSZ)

#define NDBLK 782       // ceil(NN/256)
#define XBLOCKS 1024
#define EGB   1024      // edge-gather blocks
#define CAPL  4096

// ---- workspace layout (word offsets) ----
#define P_PART  0
#define P_HIST  PARTW                    // 65536 i32 (zeroed)
#define P_CANDN (P_HIST + 65536)         // 8 (zeroed)
#define P_S8    (P_CANDN + 8)            // 512 (zeroed)
#define ZERO_LEN (65536 + 8 + 512)       // from P_HIST
#define P_FLAG  (P_S8 + 512)
#define P_THR   (P_FLAG + 8)
#define P_SV    (P_THR + 8)
#define P_D     (P_SV + 64)
#define P_DIS   (P_D + 256)
#define P_SCORE (P_DIS + NN)
#define P_CKEY  (P_SCORE + NN)
#define P_CIDX  (P_CKEY + 4096)
#define P_XT    (P_CIDX + 4096)
#define P_WW    (P_XT + 4096)

// ---- helpers (proven) ----
__device__ __forceinline__ float ldf(const void* p, int i, int bf) {
  if (bf) return __bfloat162float(((const __hip_bfloat16*)p)[i]);
  return ((const float*)p)[i];
}
__device__ __forceinline__ void stf(void* p, int i, float v, int bf) {
  if (bf) ((__hip_bfloat16*)p)[i] = __float2bfloat16(v);
  else ((float*)p)[i] = v;
}
__device__ __forceinline__ float bfu(unsigned u) {        // low 16 bits -> bf16 value
  return __uint_as_float(u << 16);
}
__device__ __forceinline__ float wsum(float v) {
#pragma unroll
  for (int m = 32; m >= 1; m >>= 1) v += __shfl_xor(v, m, 64);
  return v;
}
__device__ __forceinline__ int wsumi(int v) {
#pragma unroll
  for (int m = 32; m >= 1; m >>= 1) v += __shfl_xor(v, m, 64);
  return v;
}
__device__ __forceinline__ unsigned sortkey(float f) {
  unsigned u = __float_as_uint(f);
  return (u & 0x80000000u) ? ~u : (u | 0x80000000u);
}

// ---- dtype detector (proven) ----
__global__ void k_detect(const unsigned short* x16, int* flag) {
  __shared__ int cnt;
  if (threadIdx.x == 0) cnt = 0;
  __syncthreads();
  int ok = 0;
  for (int k = threadIdx.x; k < 512; k += 256) {
    unsigned short u = x16[2 * k];
    int e = (u >> 7) & 0xFF;
    if (u == 0 || (e >= 100 && e <= 150)) ok++;
  }
  atomicAdd(&cnt, ok);
  __syncthreads();
  if (threadIdx.x == 0) flag[0] = (cnt >= 400) ? 1 : 0;
}

// ---- bucketed degree histogram, 32KB LDS (proven round 6) ----
__global__ void k_hcol(const int* __restrict__ col, int* __restrict__ part) {
  __shared__ int lh[BSZ];
  int t = threadIdx.x;
  int b = blockIdx.x / CC, j = blockIdx.x % CC;
  for (int k = t; k < BSZ; k += 256) lh[k] = 0;
  __syncthreads();
  int base = b << BSH;
  const int4* c4 = (const int4*)col;
  for (int w0 = j * BW4; w0 < NI4; w0 += CC * BW4) {
    int end = w0 + BW4; if (end > NI4) end = NI4;
    for (int i = w0 + t; i < end; i += 256) {
      int4 v = c4[i];
      int a0 = v.x - base, a1 = v.y - base, a2 = v.z - base, a3 = v.w - base;
      if ((unsigned)a0 < (unsigned)BSZ) atomicAdd(&lh[a0], 1);
      if ((unsigned)a1 < (unsigned)BSZ) atomicAdd(&lh[a1], 1);
      if ((unsigned)a2 < (unsigned)BSZ) atomicAdd(&lh[a2], 1);
      if ((unsigned)a3 < (unsigned)BSZ) atomicAdd(&lh[a3], 1);
    }
  }
  __syncthreads();
  int* dst = part + (size_t)blockIdx.x * BSZ;
  for (int k = t; k < BSZ; k += 256) dst[k] = lh[k];
}

// ---- reduce partials -> dis; doc matvec on extra blocks (proven round 6) ----
__global__ void k_redA(const int* __restrict__ part, float* __restrict__ dis,
                       const void* docf, const void* dw, const void* db,
                       float* __restrict__ d, const int* flagp) {
  if (blockIdx.x < NDBLK) {
    int i = blockIdx.x * 256 + threadIdx.x;
    if (i < NN) {
      int b = i >> BSH, k = i & (BSZ - 1);
      const int* p = part + (size_t)b * CC * BSZ + k;
      int deg = 1;
#pragma unroll
      for (int j = 0; j < CC; j++) deg += p[(size_t)j * BSZ];
      dis[i] = rsqrtf((float)deg);
    }
  } else {
    int flag = flagp[0];
    int o = (blockIdx.x - NDBLK) * 4 + (threadIdx.x >> 6);
    int lane = threadIdx.x & 63;
    float acc = 0.f;
    for (int k = lane; k < DDIMC; k += 64) acc += ldf(docf, k, flag) * ldf(dw, o * DDIMC + k, flag);
    acc = wsum(acc);
    if (lane == 0) d[o] = fmaxf(acc + ldf(db, o, flag), 0.0f);
  }
}

// ---- NEW: direct edge-gather  s_edge = sum_e dis[row]*dis[col]*x[row]  (no atomics on nodes) ----
__global__ void k_egather(const int* __restrict__ row, const int* __restrict__ col,
                          const float* __restrict__ dis, const void* x,
                          float* __restrict__ s8, const int* flagp) {
  __shared__ float sred[4][64];
  int flag = flagp[0];
  int t = threadIdx.x;
  int w = t >> 6, lane = t & 63;
  int g = lane & 7;          // feature group: features [g*8, g*8+8)
  int sl = lane >> 3;        // edge slot 0..7
  float a0 = 0, a1 = 0, a2 = 0, a3 = 0, a4 = 0, a5 = 0, a6 = 0, a7 = 0;
  int gw = blockIdx.x * 4 + w;        // global wave id
  const int nwav = EGB * 4;
  for (int e0 = gw * 8; e0 < EE; e0 += nwav * 8) {
    int e = e0 + sl;
    if (e < EE) {
      int r = row[e], c = col[e];
      float wt = dis[r] * dis[c];
      if (flag) {
        uint4 px = *((const uint4*)((const unsigned short*)x + r * 64) + g);
        a0 += wt * bfu(px.x & 0xffff); a1 += wt * bfu(px.x >> 16);
        a2 += wt * bfu(px.y & 0xffff); a3 += wt * bfu(px.y >> 16);
        a4 += wt * bfu(px.z & 0xffff); a5 += wt * bfu(px.z >> 16);
        a6 += wt * bfu(px.w & 0xffff); a7 += wt * bfu(px.w >> 16);
      } else {
        const float4* xf = (const float4*)((const float*)x + r * 64) + g * 2;
        float4 u = xf[0], v = xf[1];
        a0 += wt * u.x; a1 += wt * u.y; a2 += wt * u.z; a3 += wt * u.w;
        a4 += wt * v.x; a5 += wt * v.y; a6 += wt * v.z; a7 += wt * v.w;
      }
    }
  }
  // reduce across the 8 slots sharing each feature group
#pragma unroll
  for (int m = 8; m <= 32; m <<= 1) {
    a0 += __shfl_xor(a0, m, 64); a1 += __shfl_xor(a1, m, 64);
    a2 += __shfl_xor(a2, m, 64); a3 += __shfl_xor(a3, m, 64);
    a4 += __shfl_xor(a4, m, 64); a5 += __shfl_xor(a5, m, 64);
    a6 += __shfl_xor(a6, m, 64); a7 += __shfl_xor(a7, m, 64);
  }
  if (sl == 0) {
    float* dst = &sred[w][g * 8];
    dst[0] = a0; dst[1] = a1; dst[2] = a2; dst[3] = a3;
    dst[4] = a4; dst[5] = a5; dst[6] = a6; dst[7] = a7;
  }
  __syncthreads();
  if (t < 64)
    atomicAdd(&s8[(blockIdx.x & 7) * 64 + t],
              sred[0][t] + sred[1][t] + sred[2][t] + sred[3][t]);
}

// ---- fused x pass (proven structure; cr = dis^2 self-loop only) ----
__global__ void k_x(const void* x, const void* pw, const float* __restrict__ dis,
                    float* __restrict__ score, int* __restrict__ hist,
                    float* __restrict__ s8, const int* flagp) {
  __shared__ float sred[4][64];
  int flag = flagp[0];
  int t = threadIdx.x;
  int lane = t & 63;
  int w = t >> 6;
  int wid = (blockIdx.x * 256 + t) >> 6;
  int nw = (gridDim.x * 256) >> 6;
  float pwl = ldf(pw, lane, flag);
  float inv = 1.0f / sqrtf(wsum(pwl * pwl));
  float sacc = 0.f;
  for (int r = wid; r < NN; r += nw) {
    float xv = ldf(x, r * 64 + lane, flag);
    float dot = wsum(xv * pwl);
    float dv = dis[r];
    sacc += dv * dv * xv;
    if (lane == 0) {
      float sc = dot * inv;
      score[r] = sc;
      atomicAdd(&hist[sortkey(sc) >> 16], 1);
    }
  }
  sred[w][lane] = sacc;
  __syncthreads();
  if (w == 0)
    atomicAdd(&s8[(blockIdx.x & 7) * 64 + lane],
              sred[0][lane] + sred[1][lane] + sred[2][lane] + sred[3][lane]);
}

// ---- threshold (proven) ----
__global__ void k_thresh(const int* __restrict__ hist, int* __restrict__ thrB,
                         const float* __restrict__ s8, float* __restrict__ svec) {
  __shared__ int part[256];
  __shared__ int segl[256];
  __shared__ int res2[2];
  int t = threadIdx.x, w = t >> 6, lane = t & 63;
  if (t < 64) {
    float a = 0.f;
    for (int r = 0; r < 8; r++) a += s8[r * 64 + t];
    svec[t] = a;
  }
  for (int m = w; m < 256; m += 4) {
    const int* hb = &hist[m * 256];
    int a = hb[lane] + hb[lane + 64] + hb[lane + 128] + hb[lane + 192];
    a = wsumi(a);
    if (lane == 0) part[m] = a;
  }
  __syncthreads();
  if (t == 0) {
    int acc = 0, seg = 0, above = 0;
    for (int b = 255; b >= 0; b--) {
      if (acc + part[b] >= 64) { seg = b; above = acc; break; }
      acc += part[b];
    }
    res2[0] = seg; res2[1] = above;
  }
  __syncthreads();
  segl[t] = hist[res2[0] * 256 + t];
  __syncthreads();
  if (t == 0) {
    int acc = res2[1], B = res2[0] * 256;
    for (int j = 255; j >= 0; j--) {
      acc += segl[j];
      if (acc >= 64) { B = res2[0] * 256 + j; break; }
    }
    thrB[0] = B;
  }
}

// ---- collect (proven) ----
__global__ void k_collect(const float* __restrict__ score, const int* __restrict__ thrB,
                          int* __restrict__ candn, unsigned* __restrict__ ckey,
                          int* __restrict__ cidx) {
  int i = blockIdx.x * blockDim.x + threadIdx.x;
  if (i >= NN) return;
  unsigned u = sortkey(score[i]);
  if ((int)(u >> 16) >= thrB[0]) {
    int p = atomicAdd(candn, 1);
    if (p < CAPL) { ckey[p] = u; cidx[p] = i; }
  }
}

// ---- top-64 (proven) ----
__global__ void k_top(const int* __restrict__ candn, const unsigned* __restrict__ ckey,
                      const int* __restrict__ cidx, const void* x,
                      float* __restrict__ xt, const int* flagp) {
  __shared__ unsigned long long keys[CAPL];
  __shared__ int perm[64];
  __shared__ float ts[64];
  int flag = flagp[0];
  int t = threadIdx.x;
  int M = candn[0];
  if (M > CAPL) M = CAPL;
  for (int j = t; j < M; j += 256)
    keys[j] = (((unsigned long long)ckey[j]) << 32) |
              (unsigned long long)(0xFFFFFFFFu - (unsigned)cidx[j]);
  __syncthreads();
  for (int j = t; j < M; j += 256) {
    unsigned long long k = keys[j];
    int rank = 0;
    for (int i = 0; i < M; i++) rank += (keys[i] > k) ? 1 : 0;
    if (rank < 64) {
      unsigned ku = (unsigned)(k >> 32);
      unsigned idx = 0xFFFFFFFFu - (unsigned)(k & 0xFFFFFFFFu);
      perm[rank] = (int)idx;
      unsigned bits = (ku & 0x80000000u) ? (ku ^ 0x80000000u) : ~ku;
      ts[rank] = tanhf(__uint_as_float(bits));
    }
  }
  __syncthreads();
  for (int q = t; q < 4096; q += 256) {
    int j = q >> 6, f = q & 63;
    xt[q] = ldf(x, perm[j] * 64 + f, flag) * ts[j];
  }
}

// ---- GRU (proven) ----
__global__ void k_gru(const float* __restrict__ xt, const void* h0g, const void* wihg,
                      const void* whhg, const void* bihg, const void* bhhg,
                      float* __restrict__ Wout, const int* flagp) {
  __shared__ float wbuf[192 * 64];
  __shared__ float xtr[256];
  __shared__ float h0r[256];
  int flag = flagp[0];
  int t = threadIdx.x;
  int j0 = blockIdx.x * 4;
  { int jj = t >> 6, f = t & 63;
    xtr[t] = xt[(j0 + jj) * 64 + f];
    h0r[t] = ldf(h0g, (j0 + jj) * 64 + f, flag); }
  for (int k = t; k < 12288; k += 256) { int f = k / 192, o = k % 192; wbuf[f * 192 + o] = ldf(wihg, o * 64 + f, flag); }
  __syncthreads();
  int jl = t >> 6, c2 = t & 63;
  float xr = 0, xz = 0, xn = 0;
  for (int f = 0; f < 64; f++) {
    float xv = xtr[jl * 64 + f];
    const float* wr = &wbuf[f * 192];
    xr += xv * wr[c2]; xz += xv * wr[64 + c2]; xn += xv * wr[128 + c2];
  }
  __syncthreads();
  for (int k = t; k < 12288; k += 256) { int f = k / 192, o = k % 192; wbuf[f * 192 + o] = ldf(whhg, o * 64 + f, flag); }
  __syncthreads();
  float hr = 0, hz = 0, hn = 0;
  for (int f = 0; f < 64; f++) {
    float hv = h0r[jl * 64 + f];
    const float* wr = &wbuf[f * 192];
    hr += hv * wr[c2]; hz += hv * wr[64 + c2]; hn += hv * wr[128 + c2];
  }
  xr += ldf(bihg, c2, flag); xz += ldf(bihg, 64 + c2, flag); xn += ldf(bihg, 128 + c2, flag);
  hr += ldf(bhhg, c2, flag); hz += ldf(bhhg, 64 + c2, flag); hn += ldf(bhhg, 128 + c2, flag);
  float rg = 1.f / (1.f + expf(-(xr + hr)));
  float zg = 1.f / (1.f + expf(-(xz + hz)));
  float nc = tanhf(xn + rg * hn);
  Wout[(j0 + jl) * 64 + c2] = (1.f - zg) * nc + zg * h0r[jl * 64 + c2];
}

// ---- tail (proven) ----
__global__ void k_tail(const float* __restrict__ svec, const float* __restrict__ Wm,
                       const float* __restrict__ d, const void* gw, const void* gb,
                       const void* lng, const void* lnb, const void* fw, const void* fb,
                       const void* tw, const void* tb, const void* tmw, const void* tmb,
                       void* out, const int* flagp) {
  __shared__ float pooled[64];
  __shared__ float lnv[512];
  __shared__ float red[256];
  __shared__ float stats[2];
  __shared__ float h1s[256];
  int flag = flagp[0];
  int t = threadIdx.x;
  if (t < 64) {
    float a = 0.f;
    for (int f = 0; f < 64; f++) a += svec[f] * Wm[f * 64 + t];
    pooled[t] = a * (1.0f / (float)NN);
  }
  __syncthreads();
  float v0 = 0;
  { float a = 0.f;
    for (int c2 = 0; c2 < 64; c2++) a += pooled[c2] * ldf(gw, t * 64 + c2, flag);
    v0 = a + ldf(gb, t, flag); }
  float v1 = d[t];
  red[t] = v0 + v1; __syncthreads();
  for (int s = 128; s > 0; s >>= 1) { if (t < s) red[t] += red[t + s]; __syncthreads(); }
  if (t == 0) stats[0] = red[0];
  __syncthreads();
  red[t] = v0 * v0 + v1 * v1; __syncthreads();
  for (int s = 128; s > 0; s >>= 1) { if (t < s) red[t] += red[t + s]; __syncthreads(); }
  if (t == 0) stats[1] = red[0];
  __syncthreads();
  float mu = stats[0] * (1.f / 512.f);
  float var = stats[1] * (1.f / 512.f) - mu * mu;
  float istd = rsqrtf(var + 1e-5f);
  lnv[t]       = (v0 - mu) * istd * ldf(lng, t, flag)       + ldf(lnb, t, flag);
  lnv[t + 256] = (v1 - mu) * istd * ldf(lng, t + 256, flag) + ldf(lnb, t + 256, flag);
  __syncthreads();
  int w = t >> 6, lane = t & 63;
  for (int o = w; o < 256; o += 4) {
    float acc = 0.f;
    for (int k = lane; k < 512; k += 64) acc += lnv[k] * ldf(fw, o * 512 + k, flag);
    acc = wsum(acc);
    if (lane == 0) h1s[o] = fmaxf(acc + ldf(fb, o, flag), 0.0f);
  }
  __syncthreads();
  for (int o = w; o < 17; o += 4) {
    float acc = 0.f;
    if (o < 16) { for (int k = lane; k < 256; k += 64) acc += h1s[k] * ldf(tw, o * 256 + k, flag); }
    else        { for (int k = lane; k < 256; k += 64) acc += h1s[k] * ldf(tmw, k, flag); }
    acc = wsum(acc);
    if (lane == 0) {
      float bias = (o < 16) ? ldf(tb, o, flag) : ldf(tmb, 0, flag);
      stf(out, o, acc + bias, flag);
    }
  }
}

extern "C" void kernel_launch(void* const* d_in, const int* in_sizes, int n_in,
                              void* d_out, int out_size, void* d_ws, size_t ws_size,
                              hipStream_t stream) {
  const void* x    = d_in[0];
  const int*  ei   = (const int*)d_in[1];
  const void* docf = d_in[2];
  const void* pw   = d_in[3];
  const void* h0   = d_in[4];
  const void* wih  = d_in[5];
  const void* whh  = d_in[6];
  const void* bih  = d_in[7];
  const void* bhh  = d_in[8];
  const void* gw   = d_in[9];
  const void* gb   = d_in[10];
  const void* dw   = d_in[11];
  const void* db   = d_in[12];
  const void* lng  = d_in[13];
  const void* lnb  = d_in[14];
  const void* fw   = d_in[15];
  const void* fb   = d_in[16];
  const void* tw   = d_in[17];
  const void* tb   = d_in[18];
  const void* tmw  = d_in[19];
  const void* tmb  = d_in[20];

  const int* row = ei;
  const int* col = ei + EE;

  float* wsf = (float*)d_ws;
  int*   wsi = (int*)d_ws;

  hipMemsetAsync(wsi + P_HIST, 0, (size_t)ZERO_LEN * 4, stream);
  k_detect<<<1, 256, 0, stream>>>((const unsigned short*)x, wsi + P_FLAG);
  k_hcol<<<NB * CC, 256, 0, stream>>>(col, wsi + P_PART);
  k_redA<<<NDBLK + 64, 256, 0, stream>>>(wsi + P_PART, wsf + P_DIS, docf, dw, db,
                                         wsf + P_D, wsi + P_FLAG);
  k_egather<<<EGB, 256, 0, stream>>>(row, col, wsf + P_DIS, x, wsf + P_S8, wsi + P_FLAG);
  k_x<<<XBLOCKS, 256, 0, stream>>>(x, pw, wsf + P_DIS, wsf + P_SCORE,
                                   wsi + P_HIST, wsf + P_S8, wsi + P_FLAG);
  k_thresh<<<1, 256, 0, stream>>>(wsi + P_HIST, wsi + P_THR, wsf + P_S8, wsf + P_SV);
  k_collect<<<NDBLK, 256, 0, stream>>>(wsf + P_SCORE, wsi + P_THR, wsi + P_CANDN,
                                       (unsigned*)(wsi + P_CKEY), wsi + P_CIDX);
  k_top<<<1, 256, 0, stream>>>(wsi + P_CANDN, (const unsigned*)(wsi + P_CKEY),
                               wsi + P_CIDX, x, wsf + P_XT, wsi + P_FLAG);
  k_gru<<<16, 256, 0, stream>>>(wsf + P_XT, h0, wih, whh, bih, bhh, wsf + P_WW, wsi + P_FLAG);
  k_tail<<<1, 256, 0, stream>>>(wsf + P_SV, wsf + P_WW, wsf + P_D, gw, gb, lng, lnb,
                                fw, fb, tw, tb, tmw, tmb, d_out, wsi + P_FLAG);
}

// Round 8
// 580.126 us; speedup vs baseline: 1.6567x; 1.1966x over previous
//
#include <hip/hip_runtime.h>
#include <hip/hip_bf16.h>

#define NN    200000
#define EE    3200000
#define DDIMC 768

#define NB    25        // node buckets
#define BSH   13
#define BSZ   8192      // nodes per bucket -> 32KB LDS histogram
#define CC    12        // edge chunks per bucket
#define NI4   800000    // EE/4 int4s
#define BW4   2048      // int4 window (32KB)
#define HTH   1024      // histogram block threads (16 waves -> latency hiding)
#define PARTW (NB * CC * BSZ)

#define NDBLK 782       // ceil(NN/256)
#define XBLOCKS 1024
#define CAPL  4096

// ---- workspace layout (word offsets); ~13.4MB total (< proven 14.7MB) ----
#define P_PART  0
#define P_HIST  PARTW                    // 65536 i32 (zeroed)
#define P_CANDN (P_HIST + 65536)         // 8 (zeroed)
#define P_S8    (P_CANDN + 8)            // 512 (zeroed)
#define ZERO_LEN (65536 + 8 + 512)       // from P_HIST
#define P_FLAG  (P_S8 + 512)
#define P_THR   (P_FLAG + 8)
#define P_SV    (P_THR + 8)
#define P_D     (P_SV + 64)
#define P_DIS   (P_D + 256)
#define P_C     (P_DIS + NN)
#define P_SCORE (P_C + NN)
#define P_CKEY  (P_SCORE + NN)
#define P_CIDX  (P_CKEY + 4096)
#define P_XT    (P_CIDX + 4096)
#define P_WW    (P_XT + 4096)

// ---- helpers (proven) ----
__device__ __forceinline__ float ldf(const void* p, int i, int bf) {
  if (bf) return __bfloat162float(((const __hip_bfloat16*)p)[i]);
  return ((const float*)p)[i];
}
__device__ __forceinline__ void stf(void* p, int i, float v, int bf) {
  if (bf) ((__hip_bfloat16*)p)[i] = __float2bfloat16(v);
  else ((float*)p)[i] = v;
}
__device__ __forceinline__ float wsum(float v) {
#pragma unroll
  for (int m = 32; m >= 1; m >>= 1) v += __shfl_xor(v, m, 64);
  return v;
}
__device__ __forceinline__ int wsumi(int v) {
#pragma unroll
  for (int m = 32; m >= 1; m >>= 1) v += __shfl_xor(v, m, 64);
  return v;
}
__device__ __forceinline__ unsigned sortkey(float f) {
  unsigned u = __float_as_uint(f);
  return (u & 0x80000000u) ? ~u : (u | 0x80000000u);
}

// ---- dtype detector (proven) ----
__global__ void k_detect(const unsigned short* x16, int* flag) {
  __shared__ int cnt;
  if (threadIdx.x == 0) cnt = 0;
  __syncthreads();
  int ok = 0;
  for (int k = threadIdx.x; k < 512; k += 256) {
    unsigned short u = x16[2 * k];
    int e = (u >> 7) & 0xFF;
    if (u == 0 || (e >= 100 && e <= 150)) ok++;
  }
  atomicAdd(&cnt, ok);
  __syncthreads();
  if (threadIdx.x == 0) flag[0] = (cnt >= 400) ? 1 : 0;
}

// ---- bucketed degree histogram (proven structure; now 1024 threads for occupancy) ----
__global__ void __launch_bounds__(HTH) k_hcol(const int* __restrict__ col, int* __restrict__ part) {
  __shared__ int lh[BSZ];
  int t = threadIdx.x;
  int b = blockIdx.x / CC, j = blockIdx.x % CC;
  for (int k = t; k < BSZ; k += HTH) lh[k] = 0;
  __syncthreads();
  int base = b << BSH;
  const int4* c4 = (const int4*)col;
  for (int w0 = j * BW4; w0 < NI4; w0 += CC * BW4) {
    int end = w0 + BW4; if (end > NI4) end = NI4;
    for (int i = w0 + t; i < end; i += HTH) {
      int4 v = c4[i];
      int a0 = v.x - base, a1 = v.y - base, a2 = v.z - base, a3 = v.w - base;
      if ((unsigned)a0 < (unsigned)BSZ) atomicAdd(&lh[a0], 1);
      if ((unsigned)a1 < (unsigned)BSZ) atomicAdd(&lh[a1], 1);
      if ((unsigned)a2 < (unsigned)BSZ) atomicAdd(&lh[a2], 1);
      if ((unsigned)a3 < (unsigned)BSZ) atomicAdd(&lh[a3], 1);
    }
  }
  __syncthreads();
  int* dst = part + (size_t)blockIdx.x * BSZ;
  for (int k = t; k < BSZ; k += HTH) dst[k] = lh[k];
}

// ---- reduce degree partials -> dis; doc matvec on extra blocks (proven) ----
__global__ void k_redA(const int* __restrict__ part, float* __restrict__ dis,
                       const void* docf, const void* dw, const void* db,
                       float* __restrict__ d, const int* flagp) {
  if (blockIdx.x < NDBLK) {
    int i = blockIdx.x * 256 + threadIdx.x;
    if (i < NN) {
      int b = i >> BSH, k = i & (BSZ - 1);
      const int* p = part + (size_t)b * CC * BSZ + k;
      int deg = 1;
#pragma unroll
      for (int j = 0; j < CC; j++) deg += p[(size_t)j * BSZ];
      dis[i] = rsqrtf((float)deg);
    }
  } else {
    int flag = flagp[0];
    int o = (blockIdx.x - NDBLK) * 4 + (threadIdx.x >> 6);
    int lane = threadIdx.x & 63;
    float acc = 0.f;
    for (int k = lane; k < DDIMC; k += 64) acc += ldf(docf, k, flag) * ldf(dw, o * DDIMC + k, flag);
    acc = wsum(acc);
    if (lane == 0) d[o] = fmaxf(acc + ldf(db, o, flag), 0.0f);
  }
}

// ---- NEW: weighted bucket histogram over row, weight = dis[col] (L2-resident 800KB table) ----
__global__ void __launch_bounds__(HTH) k_hrow(const int* __restrict__ row, const int* __restrict__ col,
                                              const float* __restrict__ dis, float* __restrict__ part) {
  __shared__ float lh[BSZ];
  int t = threadIdx.x;
  int b = blockIdx.x / CC, j = blockIdx.x % CC;
  for (int k = t; k < BSZ; k += HTH) lh[k] = 0.f;
  __syncthreads();
  int base = b << BSH;
  const int4* r4 = (const int4*)row;
  const int4* c4 = (const int4*)col;
  for (int w0 = j * BW4; w0 < NI4; w0 += CC * BW4) {
    int end = w0 + BW4; if (end > NI4) end = NI4;
    for (int i = w0 + t; i < end; i += HTH) {
      int4 r = r4[i];
      int4 c = c4[i];
      int a0 = r.x - base, a1 = r.y - base, a2 = r.z - base, a3 = r.w - base;
      if ((unsigned)a0 < (unsigned)BSZ) atomicAdd(&lh[a0], dis[c.x]);
      if ((unsigned)a1 < (unsigned)BSZ) atomicAdd(&lh[a1], dis[c.y]);
      if ((unsigned)a2 < (unsigned)BSZ) atomicAdd(&lh[a2], dis[c.z]);
      if ((unsigned)a3 < (unsigned)BSZ) atomicAdd(&lh[a3], dis[c.w]);
    }
  }
  __syncthreads();
  float* dst = part + (size_t)blockIdx.x * BSZ;
  for (int k = t; k < BSZ; k += HTH) dst[k] = lh[k];
}

// ---- reduce weighted partials -> c_i = dis_i*tacc_i + dis_i^2 (k_redA pattern) ----
__global__ void k_redB(const float* __restrict__ part, const float* __restrict__ dis,
                       float* __restrict__ c) {
  int i = blockIdx.x * 256 + threadIdx.x;
  if (i < NN) {
    int b = i >> BSH, k = i & (BSZ - 1);
    const float* p = part + (size_t)b * CC * BSZ + k;
    float s = 0.f;
#pragma unroll
    for (int j = 0; j < CC; j++) s += p[(size_t)j * BSZ];
    float dv = dis[i];
    c[i] = dv * s + dv * dv;
  }
}

// ---- fused x pass: score + histogram + s = sum c_i x_i (proven round-2/4/6 form) ----
__global__ void k_x(const void* x, const void* pw, const float* __restrict__ c,
                    float* __restrict__ score, int* __restrict__ hist,
                    float* __restrict__ s8, const int* flagp) {
  __shared__ float sred[4][64];
  int flag = flagp[0];
  int t = threadIdx.x;
  int lane = t & 63;
  int w = t >> 6;
  int wid = (blockIdx.x * 256 + t) >> 6;
  int nw = (gridDim.x * 256) >> 6;
  float pwl = ldf(pw, lane, flag);
  float inv = 1.0f / sqrtf(wsum(pwl * pwl));
  float sacc = 0.f;
  for (int r = wid; r < NN; r += nw) {
    float xv = ldf(x, r * 64 + lane, flag);
    float dot = wsum(xv * pwl);
    sacc += c[r] * xv;
    if (lane == 0) {
      float sc = dot * inv;
      score[r] = sc;
      atomicAdd(&hist[sortkey(sc) >> 16], 1);
    }
  }
  sred[w][lane] = sacc;
  __syncthreads();
  if (w == 0)
    atomicAdd(&s8[(blockIdx.x & 7) * 64 + lane],
              sred[0][lane] + sred[1][lane] + sred[2][lane] + sred[3][lane]);
}

// ---- threshold (proven) ----
__global__ void k_thresh(const int* __restrict__ hist, int* __restrict__ thrB,
                         const float* __restrict__ s8, float* __restrict__ svec) {
  __shared__ int part[256];
  __shared__ int segl[256];
  __shared__ int res2[2];
  int t = threadIdx.x, w = t >> 6, lane = t & 63;
  if (t < 64) {
    float a = 0.f;
    for (int r = 0; r < 8; r++) a += s8[r * 64 + t];
    svec[t] = a;
  }
  for (int m = w; m < 256; m += 4) {
    const int* hb = &hist[m * 256];
    int a = hb[lane] + hb[lane + 64] + hb[lane + 128] + hb[lane + 192];
    a = wsumi(a);
    if (lane == 0) part[m] = a;
  }
  __syncthreads();
  if (t == 0) {
    int acc = 0, seg = 0, above = 0;
    for (int b = 255; b >= 0; b--) {
      if (acc + part[b] >= 64) { seg = b; above = acc; break; }
      acc += part[b];
    }
    res2[0] = seg; res2[1] = above;
  }
  __syncthreads();
  segl[t] = hist[res2[0] * 256 + t];
  __syncthreads();
  if (t == 0) {
    int acc = res2[1], B = res2[0] * 256;
    for (int j = 255; j >= 0; j--) {
      acc += segl[j];
      if (acc >= 64) { B = res2[0] * 256 + j; break; }
    }
    thrB[0] = B;
  }
}

// ---- collect (proven) ----
__global__ void k_collect(const float* __restrict__ score, const int* __restrict__ thrB,
                          int* __restrict__ candn, unsigned* __restrict__ ckey,
                          int* __restrict__ cidx) {
  int i = blockIdx.x * blockDim.x + threadIdx.x;
  if (i >= NN) return;
  unsigned u = sortkey(score[i]);
  if ((int)(u >> 16) >= thrB[0]) {
    int p = atomicAdd(candn, 1);
    if (p < CAPL) { ckey[p] = u; cidx[p] = i; }
  }
}

// ---- top-64 (proven) ----
__global__ void k_top(const int* __restrict__ candn, const unsigned* __restrict__ ckey,
                      const int* __restrict__ cidx, const void* x,
                      float* __restrict__ xt, const int* flagp) {
  __shared__ unsigned long long keys[CAPL];
  __shared__ int perm[64];
  __shared__ float ts[64];
  int flag = flagp[0];
  int t = threadIdx.x;
  int M = candn[0];
  if (M > CAPL) M = CAPL;
  for (int j = t; j < M; j += 256)
    keys[j] = (((unsigned long long)ckey[j]) << 32) |
              (unsigned long long)(0xFFFFFFFFu - (unsigned)cidx[j]);
  __syncthreads();
  for (int j = t; j < M; j += 256) {
    unsigned long long k = keys[j];
    int rank = 0;
    for (int i = 0; i < M; i++) rank += (keys[i] > k) ? 1 : 0;
    if (rank < 64) {
      unsigned ku = (unsigned)(k >> 32);
      unsigned idx = 0xFFFFFFFFu - (unsigned)(k & 0xFFFFFFFFu);
      perm[rank] = (int)idx;
      unsigned bits = (ku & 0x80000000u) ? (ku ^ 0x80000000u) : ~ku;
      ts[rank] = tanhf(__uint_as_float(bits));
    }
  }
  __syncthreads();
  for (int q = t; q < 4096; q += 256) {
    int j = q >> 6, f = q & 63;
    xt[q] = ldf(x, perm[j] * 64 + f, flag) * ts[j];
  }
}

// ---- GRU (proven) ----
__global__ void k_gru(const float* __restrict__ xt, const void* h0g, const void* wihg,
                      const void* whhg, const void* bihg, const void* bhhg,
                      float* __restrict__ Wout, const int* flagp) {
  __shared__ float wbuf[192 * 64];
  __shared__ float xtr[256];
  __shared__ float h0r[256];
  int flag = flagp[0];
  int t = threadIdx.x;
  int j0 = blockIdx.x * 4;
  { int jj = t >> 6, f = t & 63;
    xtr[t] = xt[(j0 + jj) * 64 + f];
    h0r[t] = ldf(h0g, (j0 + jj) * 64 + f, flag); }
  for (int k = t; k < 12288; k += 256) { int f = k / 192, o = k % 192; wbuf[f * 192 + o] = ldf(wihg, o * 64 + f, flag); }
  __syncthreads();
  int jl = t >> 6, c2 = t & 63;
  float xr = 0, xz = 0, xn = 0;
  for (int f = 0; f < 64; f++) {
    float xv = xtr[jl * 64 + f];
    const float* wr = &wbuf[f * 192];
    xr += xv * wr[c2]; xz += xv * wr[64 + c2]; xn += xv * wr[128 + c2];
  }
  __syncthreads();
  for (int k = t; k < 12288; k += 256) { int f = k / 192, o = k % 192; wbuf[f * 192 + o] = ldf(whhg, o * 64 + f, flag); }
  __syncthreads();
  float hr = 0, hz = 0, hn = 0;
  for (int f = 0; f < 64; f++) {
    float hv = h0r[jl * 64 + f];
    const float* wr = &wbuf[f * 192];
    hr += hv * wr[c2]; hz += hv * wr[64 + c2]; hn += hv * wr[128 + c2];
  }
  xr += ldf(bihg, c2, flag); xz += ldf(bihg, 64 + c2, flag); xn += ldf(bihg, 128 + c2, flag);
  hr += ldf(bhhg, c2, flag); hz += ldf(bhhg, 64 + c2, flag); hn += ldf(bhhg, 128 + c2, flag);
  float rg = 1.f / (1.f + expf(-(xr + hr)));
  float zg = 1.f / (1.f + expf(-(xz + hz)));
  float nc = tanhf(xn + rg * hn);
  Wout[(j0 + jl) * 64 + c2] = (1.f - zg) * nc + zg * h0r[jl * 64 + c2];
}

// ---- tail (proven) ----
__global__ void k_tail(const float* __restrict__ svec, const float* __restrict__ Wm,
                       const float* __restrict__ d, const void* gw, const void* gb,
                       const void* lng, const void* lnb, const void* fw, const void* fb,
                       const void* tw, const void* tb, const void* tmw, const void* tmb,
                       void* out, const int* flagp) {
  __shared__ float pooled[64];
  __shared__ float lnv[512];
  __shared__ float red[256];
  __shared__ float stats[2];
  __shared__ float h1s[256];
  int flag = flagp[0];
  int t = threadIdx.x;
  if (t < 64) {
    float a = 0.f;
    for (int f = 0; f < 64; f++) a += svec[f] * Wm[f * 64 + t];
    pooled[t] = a * (1.0f / (float)NN);
  }
  __syncthreads();
  float v0 = 0;
  { float a = 0.f;
    for (int c2 = 0; c2 < 64; c2++) a += pooled[c2] * ldf(gw, t * 64 + c2, flag);
    v0 = a + ldf(gb, t, flag); }
  float v1 = d[t];
  red[t] = v0 + v1; __syncthreads();
  for (int s = 128; s > 0; s >>= 1) { if (t < s) red[t] += red[t + s]; __syncthreads(); }
  if (t == 0) stats[0] = red[0];
  __syncthreads();
  red[t] = v0 * v0 + v1 * v1; __syncthreads();
  for (int s = 128; s > 0; s >>= 1) { if (t < s) red[t] += red[t + s]; __syncthreads(); }
  if (t == 0) stats[1] = red[0];
  __syncthreads();
  float mu = stats[0] * (1.f / 512.f);
  float var = stats[1] * (1.f / 512.f) - mu * mu;
  float istd = rsqrtf(var + 1e-5f);
  lnv[t]       = (v0 - mu) * istd * ldf(lng, t, flag)       + ldf(lnb, t, flag);
  lnv[t + 256] = (v1 - mu) * istd * ldf(lng, t + 256, flag) + ldf(lnb, t + 256, flag);
  __syncthreads();
  int w = t >> 6, lane = t & 63;
  for (int o = w; o < 256; o += 4) {
    float acc = 0.f;
    for (int k = lane; k < 512; k += 64) acc += lnv[k] * ldf(fw, o * 512 + k, flag);
    acc = wsum(acc);
    if (lane == 0) h1s[o] = fmaxf(acc + ldf(fb, o, flag), 0.0f);
  }
  __syncthreads();
  for (int o = w; o < 17; o += 4) {
    float acc = 0.f;
    if (o < 16) { for (int k = lane; k < 256; k += 64) acc += h1s[k] * ldf(tw, o * 256 + k, flag); }
    else        { for (int k = lane; k < 256; k += 64) acc += h1s[k] * ldf(tmw, k, flag); }
    acc = wsum(acc);
    if (lane == 0) {
      float bias = (o < 16) ? ldf(tb, o, flag) : ldf(tmb, 0, flag);
      stf(out, o, acc + bias, flag);
    }
  }
}

extern "C" void kernel_launch(void* const* d_in, const int* in_sizes, int n_in,
                              void* d_out, int out_size, void* d_ws, size_t ws_size,
                              hipStream_t stream) {
  const void* x    = d_in[0];
  const int*  ei   = (const int*)d_in[1];
  const void* docf = d_in[2];
  const void* pw   = d_in[3];
  const void* h0   = d_in[4];
  const void* wih  = d_in[5];
  const void* whh  = d_in[6];
  const void* bih  = d_in[7];
  const void* bhh  = d_in[8];
  const void* gw   = d_in[9];
  const void* gb   = d_in[10];
  const void* dw   = d_in[11];
  const void* db   = d_in[12];
  const void* lng  = d_in[13];
  const void* lnb  = d_in[14];
  const void* fw   = d_in[15];
  const void* fb   = d_in[16];
  const void* tw   = d_in[17];
  const void* tb   = d_in[18];
  const void* tmw  = d_in[19];
  const void* tmb  = d_in[20];

  const int* row = ei;
  const int* col = ei + EE;

  float* wsf = (float*)d_ws;
  int*   wsi = (int*)d_ws;

  hipMemsetAsync(wsi + P_HIST, 0, (size_t)ZERO_LEN * 4, stream);
  k_detect<<<1, 256, 0, stream>>>((const unsigned short*)x, wsi + P_FLAG);
  k_hcol<<<NB * CC, HTH, 0, stream>>>(col, wsi + P_PART);
  k_redA<<<NDBLK + 64, 256, 0, stream>>>(wsi + P_PART, wsf + P_DIS, docf, dw, db,
                                         wsf + P_D, wsi + P_FLAG);
  k_hrow<<<NB * CC, HTH, 0, stream>>>(row, col, wsf + P_DIS, wsf + P_PART);
  k_redB<<<NDBLK, 256, 0, stream>>>(wsf + P_PART, wsf + P_DIS, wsf + P_C);
  k_x<<<XBLOCKS, 256, 0, stream>>>(x, pw, wsf + P_C, wsf + P_SCORE,
                                   wsi + P_HIST, wsf + P_S8, wsi + P_FLAG);
  k_thresh<<<1, 256, 0, stream>>>(wsi + P_HIST, wsi + P_THR, wsf + P_S8, wsf + P_SV);
  k_collect<<<NDBLK, 256, 0, stream>>>(wsf + P_SCORE, wsi + P_THR, wsi + P_CANDN,
                                       (unsigned*)(wsi + P_CKEY), wsi + P_CIDX);
  k_top<<<1, 256, 0, stream>>>(wsi + P_CANDN, (const unsigned*)(wsi + P_CKEY),
                               wsi + P_CIDX, x, wsf + P_XT, wsi + P_FLAG);
  k_gru<<<16, 256, 0, stream>>>(wsf + P_XT, h0, wih, whh, bih, bhh, wsf + P_WW, wsi + P_FLAG);
  k_tail<<<1, 256, 0, stream>>>(wsf + P_SV, wsf + P_WW, wsf + P_D, gw, gb, lng, lnb,
                                fw, fb, tw, tb, tmw, tmb, d_out, wsi + P_FLAG);
}

// Round 9
// 497.511 us; speedup vs baseline: 1.9318x; 1.1661x over previous
//
#include <hip/hip_runtime.h>
#include <hip/hip_bf16.h>

#define NN    200000
#define EE    3200000
#define DDIMC 768

#define NB    25        // node buckets
#define BSH   13
#define BSZ   8192      // nodes per bucket -> 32KB LDS histogram
#define CC    12        // edge chunks per bucket
#define NI4   800000    // EE/4 int4s
#define BW4   2048      // int4 window (32KB)
#define HTH   1024      // histogram block threads
#define PARTW (NB * CC * BSZ)

#define NDBLK 782       // ceil(NN/256)
#define XBLOCKS 1024
#define CAPL  4096

// ---- workspace layout (word offsets) ----
#define P_PART  0
#define P_HIST  PARTW                    // 65536 i32 (zeroed)
#define P_CANDN (P_HIST + 65536)         // 8 (zeroed)
#define P_S8    (P_CANDN + 8)            // 512 (zeroed)
#define ZERO_LEN (65536 + 8 + 512)       // from P_HIST
#define P_FLAG  (P_S8 + 512)
#define P_THR   (P_FLAG + 8)
#define P_SV    (P_THR + 8)
#define P_D     (P_SV + 64)
#define P_DIS   (P_D + 256)
#define P_C     (P_DIS + NN)
#define P_SCORE (P_C + NN)
#define P_CKEY  (P_SCORE + NN)
#define P_CIDX  (P_CKEY + 4096)
#define P_XT    (P_CIDX + 4096)
#define P_WW    (P_XT + 4096)
#define P_G     (P_WW + 4096)            // 256 f32
#define P_LNV   (P_G + 256)              // 512 f32
#define P_H1    (P_LNV + 512)            // 256 f32

// ---- helpers (proven) ----
__device__ __forceinline__ float ldf(const void* p, int i, int bf) {
  if (bf) return __bfloat162float(((const __hip_bfloat16*)p)[i]);
  return ((const float*)p)[i];
}
__device__ __forceinline__ void stf(void* p, int i, float v, int bf) {
  if (bf) ((__hip_bfloat16*)p)[i] = __float2bfloat16(v);
  else ((float*)p)[i] = v;
}
__device__ __forceinline__ float bfu(unsigned u) {   // low 16 bits -> bf16 value
  return __uint_as_float(u << 16);
}
__device__ __forceinline__ float wsum(float v) {
#pragma unroll
  for (int m = 32; m >= 1; m >>= 1) v += __shfl_xor(v, m, 64);
  return v;
}
__device__ __forceinline__ int wsumi(int v) {
#pragma unroll
  for (int m = 32; m >= 1; m >>= 1) v += __shfl_xor(v, m, 64);
  return v;
}
__device__ __forceinline__ unsigned sortkey(float f) {
  unsigned u = __float_as_uint(f);
  return (u & 0x80000000u) ? ~u : (u | 0x80000000u);
}

// ---- dtype detector (proven) ----
__global__ void k_detect(const unsigned short* x16, int* flag) {
  __shared__ int cnt;
  if (threadIdx.x == 0) cnt = 0;
  __syncthreads();
  int ok = 0;
  for (int k = threadIdx.x; k < 512; k += 256) {
    unsigned short u = x16[2 * k];
    int e = (u >> 7) & 0xFF;
    if (u == 0 || (e >= 100 && e <= 150)) ok++;
  }
  atomicAdd(&cnt, ok);
  __syncthreads();
  if (threadIdx.x == 0) flag[0] = (cnt >= 400) ? 1 : 0;
}

// ---- bucketed degree histogram (proven) ----
__global__ void __launch_bounds__(HTH) k_hcol(const int* __restrict__ col, int* __restrict__ part) {
  __shared__ int lh[BSZ];
  int t = threadIdx.x;
  int b = blockIdx.x / CC, j = blockIdx.x % CC;
  for (int k = t; k < BSZ; k += HTH) lh[k] = 0;
  __syncthreads();
  int base = b << BSH;
  const int4* c4 = (const int4*)col;
  for (int w0 = j * BW4; w0 < NI4; w0 += CC * BW4) {
    int end = w0 + BW4; if (end > NI4) end = NI4;
    for (int i = w0 + t; i < end; i += HTH) {
      int4 v = c4[i];
      int a0 = v.x - base, a1 = v.y - base, a2 = v.z - base, a3 = v.w - base;
      if ((unsigned)a0 < (unsigned)BSZ) atomicAdd(&lh[a0], 1);
      if ((unsigned)a1 < (unsigned)BSZ) atomicAdd(&lh[a1], 1);
      if ((unsigned)a2 < (unsigned)BSZ) atomicAdd(&lh[a2], 1);
      if ((unsigned)a3 < (unsigned)BSZ) atomicAdd(&lh[a3], 1);
    }
  }
  __syncthreads();
  int* dst = part + (size_t)blockIdx.x * BSZ;
  for (int k = t; k < BSZ; k += HTH) dst[k] = lh[k];
}

// ---- reduce degree partials -> dis; doc matvec on extra blocks (proven) ----
__global__ void k_redA(const int* __restrict__ part, float* __restrict__ dis,
                       const void* docf, const void* dw, const void* db,
                       float* __restrict__ d, const int* flagp) {
  if (blockIdx.x < NDBLK) {
    int i = blockIdx.x * 256 + threadIdx.x;
    if (i < NN) {
      int b = i >> BSH, k = i & (BSZ - 1);
      const int* p = part + (size_t)b * CC * BSZ + k;
      int deg = 1;
#pragma unroll
      for (int j = 0; j < CC; j++) deg += p[(size_t)j * BSZ];
      dis[i] = rsqrtf((float)deg);
    }
  } else {
    int flag = flagp[0];
    int o = (blockIdx.x - NDBLK) * 4 + (threadIdx.x >> 6);
    int lane = threadIdx.x & 63;
    float acc = 0.f;
    for (int k = lane; k < DDIMC; k += 64) acc += ldf(docf, k, flag) * ldf(dw, o * DDIMC + k, flag);
    acc = wsum(acc);
    if (lane == 0) d[o] = fmaxf(acc + ldf(db, o, flag), 0.0f);
  }
}

// ---- weighted bucket histogram over row, weight = dis[col] (proven) ----
__global__ void __launch_bounds__(HTH) k_hrow(const int* __restrict__ row, const int* __restrict__ col,
                                              const float* __restrict__ dis, float* __restrict__ part) {
  __shared__ float lh[BSZ];
  int t = threadIdx.x;
  int b = blockIdx.x / CC, j = blockIdx.x % CC;
  for (int k = t; k < BSZ; k += HTH) lh[k] = 0.f;
  __syncthreads();
  int base = b << BSH;
  const int4* r4 = (const int4*)row;
  const int4* c4 = (const int4*)col;
  for (int w0 = j * BW4; w0 < NI4; w0 += CC * BW4) {
    int end = w0 + BW4; if (end > NI4) end = NI4;
    for (int i = w0 + t; i < end; i += HTH) {
      int4 r = r4[i];
      int4 c = c4[i];
      int a0 = r.x - base, a1 = r.y - base, a2 = r.z - base, a3 = r.w - base;
      if ((unsigned)a0 < (unsigned)BSZ) atomicAdd(&lh[a0], dis[c.x]);
      if ((unsigned)a1 < (unsigned)BSZ) atomicAdd(&lh[a1], dis[c.y]);
      if ((unsigned)a2 < (unsigned)BSZ) atomicAdd(&lh[a2], dis[c.z]);
      if ((unsigned)a3 < (unsigned)BSZ) atomicAdd(&lh[a3], dis[c.w]);
    }
  }
  __syncthreads();
  float* dst = part + (size_t)blockIdx.x * BSZ;
  for (int k = t; k < BSZ; k += HTH) dst[k] = lh[k];
}

// ---- reduce weighted partials -> c_i = dis_i*tacc_i + dis_i^2 (proven) ----
__global__ void k_redB(const float* __restrict__ part, const float* __restrict__ dis,
                       float* __restrict__ c) {
  int i = blockIdx.x * 256 + threadIdx.x;
  if (i < NN) {
    int b = i >> BSH, k = i & (BSZ - 1);
    const float* p = part + (size_t)b * CC * BSZ + k;
    float s = 0.f;
#pragma unroll
    for (int j = 0; j < CC; j++) s += p[(size_t)j * BSZ];
    float dv = dis[i];
    c[i] = dv * s + dv * dv;
  }
}

// ---- fused x pass (proven) ----
__global__ void k_x(const void* x, const void* pw, const float* __restrict__ c,
                    float* __restrict__ score, int* __restrict__ hist,
                    float* __restrict__ s8, const int* flagp) {
  __shared__ float sred[4][64];
  int flag = flagp[0];
  int t = threadIdx.x;
  int lane = t & 63;
  int w = t >> 6;
  int wid = (blockIdx.x * 256 + t) >> 6;
  int nw = (gridDim.x * 256) >> 6;
  float pwl = ldf(pw, lane, flag);
  float inv = 1.0f / sqrtf(wsum(pwl * pwl));
  float sacc = 0.f;
  for (int r = wid; r < NN; r += nw) {
    float xv = ldf(x, r * 64 + lane, flag);
    float dot = wsum(xv * pwl);
    sacc += c[r] * xv;
    if (lane == 0) {
      float sc = dot * inv;
      score[r] = sc;
      atomicAdd(&hist[sortkey(sc) >> 16], 1);
    }
  }
  sred[w][lane] = sacc;
  __syncthreads();
  if (w == 0)
    atomicAdd(&s8[(blockIdx.x & 7) * 64 + lane],
              sred[0][lane] + sred[1][lane] + sred[2][lane] + sred[3][lane]);
}

// ---- threshold (proven) ----
__global__ void k_thresh(const int* __restrict__ hist, int* __restrict__ thrB,
                         const float* __restrict__ s8, float* __restrict__ svec) {
  __shared__ int part[256];
  __shared__ int segl[256];
  __shared__ int res2[2];
  int t = threadIdx.x, w = t >> 6, lane = t & 63;
  if (t < 64) {
    float a = 0.f;
    for (int r = 0; r < 8; r++) a += s8[r * 64 + t];
    svec[t] = a;
  }
  for (int m = w; m < 256; m += 4) {
    const int* hb = &hist[m * 256];
    int a = hb[lane] + hb[lane + 64] + hb[lane + 128] + hb[lane + 192];
    a = wsumi(a);
    if (lane == 0) part[m] = a;
  }
  __syncthreads();
  if (t == 0) {
    int acc = 0, seg = 0, above = 0;
    for (int b = 255; b >= 0; b--) {
      if (acc + part[b] >= 64) { seg = b; above = acc; break; }
      acc += part[b];
    }
    res2[0] = seg; res2[1] = above;
  }
  __syncthreads();
  segl[t] = hist[res2[0] * 256 + t];
  __syncthreads();
  if (t == 0) {
    int acc = res2[1], B = res2[0] * 256;
    for (int j = 255; j >= 0; j--) {
      acc += segl[j];
      if (acc >= 64) { B = res2[0] * 256 + j; break; }
    }
    thrB[0] = B;
  }
}

// ---- collect (proven) ----
__global__ void k_collect(const float* __restrict__ score, const int* __restrict__ thrB,
                          int* __restrict__ candn, unsigned* __restrict__ ckey,
                          int* __restrict__ cidx) {
  int i = blockIdx.x * blockDim.x + threadIdx.x;
  if (i >= NN) return;
  unsigned u = sortkey(score[i]);
  if ((int)(u >> 16) >= thrB[0]) {
    int p = atomicAdd(candn, 1);
    if (p < CAPL) { ckey[p] = u; cidx[p] = i; }
  }
}

// ---- top-64 (proven) ----
__global__ void k_top(const int* __restrict__ candn, const unsigned* __restrict__ ckey,
                      const int* __restrict__ cidx, const void* x,
                      float* __restrict__ xt, const int* flagp) {
  __shared__ unsigned long long keys[CAPL];
  __shared__ int perm[64];
  __shared__ float ts[64];
  int flag = flagp[0];
  int t = threadIdx.x;
  int M = candn[0];
  if (M > CAPL) M = CAPL;
  for (int j = t; j < M; j += 256)
    keys[j] = (((unsigned long long)ckey[j]) << 32) |
              (unsigned long long)(0xFFFFFFFFu - (unsigned)cidx[j]);
  __syncthreads();
  for (int j = t; j < M; j += 256) {
    unsigned long long k = keys[j];
    int rank = 0;
    for (int i = 0; i < M; i++) rank += (keys[i] > k) ? 1 : 0;
    if (rank < 64) {
      unsigned ku = (unsigned)(k >> 32);
      unsigned idx = 0xFFFFFFFFu - (unsigned)(k & 0xFFFFFFFFu);
      perm[rank] = (int)idx;
      unsigned bits = (ku & 0x80000000u) ? (ku ^ 0x80000000u) : ~ku;
      ts[rank] = tanhf(__uint_as_float(bits));
    }
  }
  __syncthreads();
  for (int q = t; q < 4096; q += 256) {
    int j = q >> 6, f = q & 63;
    xt[q] = ldf(x, perm[j] * 64 + f, flag) * ts[j];
  }
}

// ---- GRU (proven) ----
__global__ void k_gru(const float* __restrict__ xt, const void* h0g, const void* wihg,
                      const void* whhg, const void* bihg, const void* bhhg,
                      float* __restrict__ Wout, const int* flagp) {
  __shared__ float wbuf[192 * 64];
  __shared__ float xtr[256];
  __shared__ float h0r[256];
  int flag = flagp[0];
  int t = threadIdx.x;
  int j0 = blockIdx.x * 4;
  { int jj = t >> 6, f = t & 63;
    xtr[t] = xt[(j0 + jj) * 64 + f];
    h0r[t] = ldf(h0g, (j0 + jj) * 64 + f, flag); }
  for (int k = t; k < 12288; k += 256) { int f = k / 192, o = k % 192; wbuf[f * 192 + o] = ldf(wihg, o * 64 + f, flag); }
  __syncthreads();
  int jl = t >> 6, c2 = t & 63;
  float xr = 0, xz = 0, xn = 0;
  for (int f = 0; f < 64; f++) {
    float xv = xtr[jl * 64 + f];
    const float* wr = &wbuf[f * 192];
    xr += xv * wr[c2]; xz += xv * wr[64 + c2]; xn += xv * wr[128 + c2];
  }
  __syncthreads();
  for (int k = t; k < 12288; k += 256) { int f = k / 192, o = k % 192; wbuf[f * 192 + o] = ldf(whhg, o * 64 + f, flag); }
  __syncthreads();
  float hr = 0, hz = 0, hn = 0;
  for (int f = 0; f < 64; f++) {
    float hv = h0r[jl * 64 + f];
    const float* wr = &wbuf[f * 192];
    hr += hv * wr[c2]; hz += hv * wr[64 + c2]; hn += hv * wr[128 + c2];
  }
  xr += ldf(bihg, c2, flag); xz += ldf(bihg, 64 + c2, flag); xn += ldf(bihg, 128 + c2, flag);
  hr += ldf(bhhg, c2, flag); hz += ldf(bhhg, 64 + c2, flag); hn += ldf(bhhg, 128 + c2, flag);
  float rg = 1.f / (1.f + expf(-(xr + hr)));
  float zg = 1.f / (1.f + expf(-(xz + hz)));
  float nc = tanhf(xn + rg * hn);
  Wout[(j0 + jl) * 64 + c2] = (1.f - zg) * nc + zg * h0r[jl * 64 + c2];
}

// ---- NEW tail stage 1: g[o] = pooled @ gnn_fc_w.T + gnn_fc_b  (64 blocks) ----
__global__ void k_g(const float* __restrict__ svec, const float* __restrict__ Wm,
                    const void* gw, const void* gb, float* __restrict__ g,
                    const int* flagp) {
  __shared__ float pooled[64];
  int flag = flagp[0];
  int t = threadIdx.x, w = t >> 6, lane = t & 63;
  if (t < 64) {
    float a = 0.f;
    for (int f = 0; f < 64; f++) a += svec[f] * Wm[f * 64 + t];
    pooled[t] = a * (1.0f / (float)NN);
  }
  __syncthreads();
  int o = blockIdx.x * 4 + w;      // 0..255
  float acc = pooled[lane] * ldf(gw, o * 64 + lane, flag);
  acc = wsum(acc);
  if (lane == 0) g[o] = acc + ldf(gb, o, flag);
}

// ---- NEW tail stage 2: layernorm over [g | d] -> lnv (1 block, tiny traffic) ----
__global__ void k_ln(const float* __restrict__ g, const float* __restrict__ d,
                     const void* lng, const void* lnb, float* __restrict__ lnv,
                     const int* flagp) {
  __shared__ float red[256];
  __shared__ float stats[2];
  int flag = flagp[0];
  int t = threadIdx.x;
  float v0 = g[t], v1 = d[t];
  red[t] = v0 + v1; __syncthreads();
  for (int s = 128; s > 0; s >>= 1) { if (t < s) red[t] += red[t + s]; __syncthreads(); }
  if (t == 0) stats[0] = red[0];
  __syncthreads();
  red[t] = v0 * v0 + v1 * v1; __syncthreads();
  for (int s = 128; s > 0; s >>= 1) { if (t < s) red[t] += red[t + s]; __syncthreads(); }
  if (t == 0) stats[1] = red[0];
  __syncthreads();
  float mu = stats[0] * (1.f / 512.f);
  float var = stats[1] * (1.f / 512.f) - mu * mu;
  float istd = rsqrtf(var + 1e-5f);
  lnv[t]       = (v0 - mu) * istd * ldf(lng, t, flag)       + ldf(lnb, t, flag);
  lnv[t + 256] = (v1 - mu) * istd * ldf(lng, t + 256, flag) + ldf(lnb, t + 256, flag);
}

// ---- NEW tail stage 3: h1 = relu(lnv @ fusion_w.T + fb) (64 blocks, uint4 row loads) ----
__global__ void k_fuse(const float* __restrict__ lnv, const void* fw, const void* fb,
                       float* __restrict__ h1, const int* flagp) {
  __shared__ float lv[512];
  int flag = flagp[0];
  int t = threadIdx.x, w = t >> 6, lane = t & 63;
  lv[t] = lnv[t]; lv[t + 256] = lnv[t + 256];
  __syncthreads();
  int o = blockIdx.x * 4 + w;      // 0..255
  float acc = 0.f;
  if (flag) {
    uint4 u = *((const uint4*)((const unsigned short*)fw + o * 512) + lane);  // 8 bf16
    const float* l = &lv[lane * 8];
    acc = bfu(u.x & 0xffff) * l[0] + bfu(u.x >> 16) * l[1]
        + bfu(u.y & 0xffff) * l[2] + bfu(u.y >> 16) * l[3]
        + bfu(u.z & 0xffff) * l[4] + bfu(u.z >> 16) * l[5]
        + bfu(u.w & 0xffff) * l[6] + bfu(u.w >> 16) * l[7];
  } else {
    const float4* fv = (const float4*)((const float*)fw + o * 512);
    float4 a = fv[lane * 2], b = fv[lane * 2 + 1];
    const float* l = &lv[lane * 8];
    acc = a.x * l[0] + a.y * l[1] + a.z * l[2] + a.w * l[3]
        + b.x * l[4] + b.y * l[5] + b.z * l[6] + b.w * l[7];
  }
  acc = wsum(acc);
  if (lane == 0) h1[o] = fmaxf(acc + ldf(fb, o, flag), 0.0f);
}

// ---- NEW tail stage 4: task + time heads (5 blocks) ----
__global__ void k_out(const float* __restrict__ h1, const void* tw, const void* tb,
                      const void* tmw, const void* tmb, void* out, const int* flagp) {
  int flag = flagp[0];
  int t = threadIdx.x, w = t >> 6, lane = t & 63;
  int o = blockIdx.x * 4 + w;
  if (o >= 17) return;
  float acc = 0.f;
  if (o < 16) { for (int k = lane; k < 256; k += 64) acc += h1[k] * ldf(tw, o * 256 + k, flag); }
  else        { for (int k = lane; k < 256; k += 64) acc += h1[k] * ldf(tmw, k, flag); }
  acc = wsum(acc);
  if (lane == 0) {
    float bias = (o < 16) ? ldf(tb, o, flag) : ldf(tmb, 0, flag);
    stf(out, o, acc + bias, flag);
  }
}

extern "C" void kernel_launch(void* const* d_in, const int* in_sizes, int n_in,
                              void* d_out, int out_size, void* d_ws, size_t ws_size,
                              hipStream_t stream) {
  const void* x    = d_in[0];
  const int*  ei   = (const int*)d_in[1];
  const void* docf = d_in[2];
  const void* pw   = d_in[3];
  const void* h0   = d_in[4];
  const void* wih  = d_in[5];
  const void* whh  = d_in[6];
  const void* bih  = d_in[7];
  const void* bhh  = d_in[8];
  const void* gw   = d_in[9];
  const void* gb   = d_in[10];
  const void* dw   = d_in[11];
  const void* db   = d_in[12];
  const void* lng  = d_in[13];
  const void* lnb  = d_in[14];
  const void* fw   = d_in[15];
  const void* fb   = d_in[16];
  const void* tw   = d_in[17];
  const void* tb   = d_in[18];
  const void* tmw  = d_in[19];
  const void* tmb  = d_in[20];

  const int* row = ei;
  const int* col = ei + EE;

  float* wsf = (float*)d_ws;
  int*   wsi = (int*)d_ws;

  hipMemsetAsync(wsi + P_HIST, 0, (size_t)ZERO_LEN * 4, stream);
  k_detect<<<1, 256, 0, stream>>>((const unsigned short*)x, wsi + P_FLAG);
  k_hcol<<<NB * CC, HTH, 0, stream>>>(col, wsi + P_PART);
  k_redA<<<NDBLK + 64, 256, 0, stream>>>(wsi + P_PART, wsf + P_DIS, docf, dw, db,
                                         wsf + P_D, wsi + P_FLAG);
  k_hrow<<<NB * CC, HTH, 0, stream>>>(row, col, wsf + P_DIS, wsf + P_PART);
  k_redB<<<NDBLK, 256, 0, stream>>>(wsf + P_PART, wsf + P_DIS, wsf + P_C);
  k_x<<<XBLOCKS, 256, 0, stream>>>(x, pw, wsf + P_C, wsf + P_SCORE,
                                   wsi + P_HIST, wsf + P_S8, wsi + P_FLAG);
  k_thresh<<<1, 256, 0, stream>>>(wsi + P_HIST, wsi + P_THR, wsf + P_S8, wsf + P_SV);
  k_collect<<<NDBLK, 256, 0, stream>>>(wsf + P_SCORE, wsi + P_THR, wsi + P_CANDN,
                                       (unsigned*)(wsi + P_CKEY), wsi + P_CIDX);
  k_top<<<1, 256, 0, stream>>>(wsi + P_CANDN, (const unsigned*)(wsi + P_CKEY),
                               wsi + P_CIDX, x, wsf + P_XT, wsi + P_FLAG);
  k_gru<<<16, 256, 0, stream>>>(wsf + P_XT, h0, wih, whh, bih, bhh, wsf + P_WW, wsi + P_FLAG);
  k_g<<<64, 256, 0, stream>>>(wsf + P_SV, wsf + P_WW, gw, gb, wsf + P_G, wsi + P_FLAG);
  k_ln<<<1, 256, 0, stream>>>(wsf + P_G, wsf + P_D, lng, lnb, wsf + P_LNV, wsi + P_FLAG);
  k_fuse<<<64, 256, 0, stream>>>(wsf + P_LNV, fw, fb, wsf + P_H1, wsi + P_FLAG);
  k_out<<<5, 256, 0, stream>>>(wsf + P_H1, tw, tb, tmw, tmb, d_out, wsi + P_FLAG);
}